// Round 9
// baseline (195.110 us; speedup 1.0000x reference)
//
#include <hip/hip_runtime.h>
#include <math.h>

typedef unsigned short u16;
typedef unsigned int u32;
typedef __attribute__((ext_vector_type(8))) short bf16x8_t;
typedef __attribute__((ext_vector_type(4))) float f32x4_t;
typedef __attribute__((ext_vector_type(16))) float f32x16_t;

#define S_LEN  2048
#define NH     16
#define DK     64
#define DMODEL 1024
#define MROWS  4096   // B*S
#define LOG2E  1.44269504088896f

__device__ inline u16 f2b(float f) {
  union { float f; u32 u; } c; c.f = f;
  u32 u = c.u;
  return (u16)((u + 0x7fffu + ((u >> 16) & 1u)) >> 16);  // RNE bf16
}

__device__ __forceinline__ float fexp2(float x) {
#if __has_builtin(__builtin_amdgcn_exp2f)
  return __builtin_amdgcn_exp2f(x);
#else
  return exp2f(x);
#endif
}

__device__ __forceinline__ u32 cvtpk(float lo, float hi) {
  u32 r;
  asm("v_cvt_pk_bf16_f32 %0, %1, %2" : "=v"(r) : "v"(lo), "v"(hi));
  return r;
}

// swap x's high-32-lane half with y's low-32-lane half (gfx950 v_permlane32_swap_b32)
__device__ __forceinline__ void plswap(u32 &x, u32 &y) {
  asm("v_permlane32_swap_b32 %0, %1" : "+v"(x), "+v"(y));
}

// ---------------- global -> LDS DMA: wave-uniform LDS base, lane deposits 16B at base + lane*16 ----------------
__device__ __forceinline__ void stage16(const u16* gp_lane, u16* lds_base) {
#if __has_builtin(__builtin_amdgcn_global_load_lds)
  __builtin_amdgcn_global_load_lds((const __attribute__((address_space(1))) u32*)gp_lane,
                                   (__attribute__((address_space(3))) u32*)lds_base, 16, 0, 0);
#else
  *(uint4*)(lds_base + (threadIdx.x & 63) * 8) = *(const uint4*)gp_lane;
#endif
}

// ---------------- fused prep: cast x, transpose+cast 4 weights, bias table ----------------
__global__ void prep_kernel(const float* __restrict__ x,
                            const float* __restrict__ Wq, const float* __restrict__ Wk,
                            const float* __restrict__ Wv, const float* __restrict__ Wo,
                            const float* __restrict__ rel,
                            u16* __restrict__ xb, u16* __restrict__ Wall,
                            u16* __restrict__ Wto, float* __restrict__ btab) {
  __shared__ float tile[32][33];
  const int bid = blockIdx.x, t = threadIdx.x;
  if (bid < 4096) {
    int i = (bid * 256 + t) * 4;
    float4 v = *(const float4*)(x + i);
    ushort4 o;
    o.x = f2b(v.x); o.y = f2b(v.y); o.z = f2b(v.z); o.w = f2b(v.w);
    *(ushort4*)(xb + i) = o;
  } else if (bid < 8192) {
    int bid2 = bid - 4096;
    int z = bid2 >> 10, rem = bid2 & 1023;
    const float* W; u16* Wt;
    switch (z) {
      case 0: W = Wq; Wt = Wall; break;
      case 1: W = Wk; Wt = Wall + (size_t)DMODEL * DMODEL; break;
      case 2: W = Wv; Wt = Wall + (size_t)2 * DMODEL * DMODEL; break;
      default: W = Wo; Wt = Wto; break;
    }
    int bc = (rem & 31) * 32, br = (rem >> 5) * 32;
    int tx = t & 31, ty = t >> 5;
    #pragma unroll
    for (int yy = 0; yy < 32; yy += 8)
      tile[ty + yy][tx] = W[(size_t)(br + ty + yy) * DMODEL + bc + tx];
    __syncthreads();
    #pragma unroll
    for (int yy = 0; yy < 32; yy += 8)
      Wt[(size_t)(bc + ty + yy) * DMODEL + br + tx] = f2b(tile[tx][ty + yy]);
  } else {
    // bias table: btab[h][delta+2047] = (bias(h,delta) - 16) * log2(e)   [exp2-domain]
    int idx = (bid - 8192) * 256 + t;
    if (idx < NH * 4095) {
      int h = idx / 4095;
      int dpos = idx - h * 4095;
      int delta = dpos - 2047;               // j - i; reference n = i - j
      int ret = (delta > 0) ? 16 : 0;
      int n = delta < 0 ? -delta : delta;
      int bucket;
      if (n < 8) {
        bucket = ret + n;
      } else {
        float vf = logf((float)n * 0.125f) / 2.7725887222397811f * 8.0f;
        int vil = 8 + (int)vf;
        bucket = ret + (vil < 15 ? vil : 15);
      }
      btab[idx] = (rel[bucket * NH + h] - 16.0f) * LOG2E;
    }
  }
}

// ---------------- bf16 MFMA GEMM ----------------
// MODE 1: fused QKV, 128x128 tile, BK=64 (R9: was 32 -- halves barrier-drain count, doubles MFMA
//         per phase; LDS 32 KB linear [128][64], global_load_lds DMA, grid (32,24)=768=3/CU).
// MODE 0: out-projection, 128x64 tile, grid (32,16)=512 blocks=2/CU; manual staging + register
//         prefetch (R8-proven, -5 us vs 128x128 @ 1/CU).
#define GSTR 56   // manual-path LDS row stride (112 B): 16B-aligned, 2-way bank aliasing (free)
template <int MODE>
__global__ __launch_bounds__(256) void gemm128_kernel(const u16* __restrict__ A,
                                                      const u16* __restrict__ Bt,
                                                      float* __restrict__ C,
                                                      u16* __restrict__ q16,
                                                      u16* __restrict__ k16,
                                                      u16* __restrict__ vt16) {
  constexpr int ABSZ = (MODE == 1) ? 8192 : 128 * GSTR;
  constexpr int BSZ  = (MODE == 1) ? 8192 : 64 * GSTR;
  constexpr int FSTR = (MODE == 1) ? 64 : GSTR;
  __shared__ __align__(16) u16 As[ABSZ];
  __shared__ __align__(16) u16 Bs[BSZ];
  const int t = threadIdx.x, w = t >> 6, l = t & 63;
  const int c = l & 15, quad = l >> 4;
  const int m0 = blockIdx.x * 128;
  const int n0 = blockIdx.y * ((MODE == 1) ? 128 : 64);
  const int wm = (w & 1) * 64;
  const int wn = (w >> 1) * ((MODE == 1) ? 64 : 32);

  f32x4_t acc[16] = {};

  if constexpr (MODE == 1) {
    // BK=64 DMA map: wave w stages rows w*32..+31 of A and B in 4 slabs of 8 rows;
    // lane l -> row offset l>>3, col (l&7)*8 (matches stage16's linear base+lane*16 dest)
    const int sr8 = l >> 3;          // 0..7
    const int k8 = (l & 7) * 8;      // 0..56
    const u16* AgB = A  + (size_t)(m0 + w * 32 + sr8) * DMODEL + k8;
    const u16* BgB = Bt + (size_t)(n0 + w * 32 + sr8) * DMODEL + k8;
    u16* Al = As + w * 2048;   // w*32 rows * 64 cols
    u16* Bl = Bs + w * 2048;
    for (int k0 = 0; k0 < DMODEL; k0 += 64) {
      __syncthreads();   // prior frag reads done
      #pragma unroll
      for (int s = 0; s < 4; ++s) {
        stage16(AgB + (size_t)s * 8 * DMODEL + k0, Al + s * 512);
        stage16(BgB + (size_t)s * 8 * DMODEL + k0, Bl + s * 512);
      }
      __syncthreads();   // vmcnt drain before barrier completes staging
      #pragma unroll
      for (int kc = 0; kc < 2; ++kc) {
        bf16x8_t af[4], bfr[4];
        #pragma unroll
        for (int i = 0; i < 4; ++i) {
          af[i]  = *(const bf16x8_t*)(As + (wm + i * 16 + c) * FSTR + kc * 32 + quad * 8);
          bfr[i] = *(const bf16x8_t*)(Bs + (wn + i * 16 + c) * FSTR + kc * 32 + quad * 8);
        }
        #pragma unroll
        for (int mt = 0; mt < 4; ++mt)
          #pragma unroll
          for (int nt = 0; nt < 4; ++nt)
            acc[mt * 4 + nt] = __builtin_amdgcn_mfma_f32_16x16x32_bf16(af[mt], bfr[nt], acc[mt * 4 + nt], 0, 0, 0);
      }
    }
  } else {
    // manual staging + register prefetch; A: 128x32, B: 64x32 per K-step
    const int sr = t >> 2;              // 0..63
    const int k8 = (t & 3) * 8;
    const u16* Ag0 = A  + (size_t)(m0 + sr) * DMODEL + k8;
    const u16* Ag1 = Ag0 + (size_t)64 * DMODEL;
    const u16* Bg0 = Bt + (size_t)(n0 + sr) * DMODEL + k8;
    u16* Al0 = As + sr * GSTR + k8;
    u16* Al1 = Al0 + 64 * GSTR;
    u16* Bl0 = Bs + sr * GSTR + k8;

    uint4 a0 = *(const uint4*)Ag0, a1 = *(const uint4*)Ag1;
    uint4 b0 = *(const uint4*)Bg0;
    for (int k0 = 0; k0 < DMODEL; k0 += 32) {
      __syncthreads();
      *(uint4*)Al0 = a0; *(uint4*)Al1 = a1;
      *(uint4*)Bl0 = b0;
      __syncthreads();
      if (k0 + 32 < DMODEL) {
        a0 = *(const uint4*)(Ag0 + k0 + 32);
        a1 = *(const uint4*)(Ag1 + k0 + 32);
        b0 = *(const uint4*)(Bg0 + k0 + 32);
      }
      bf16x8_t af[4], bfr[2];
      #pragma unroll
      for (int i = 0; i < 4; ++i)
        af[i] = *(const bf16x8_t*)(As + (wm + i * 16 + c) * FSTR + quad * 8);
      #pragma unroll
      for (int i = 0; i < 2; ++i)
        bfr[i] = *(const bf16x8_t*)(Bs + (wn + i * 16 + c) * FSTR + quad * 8);
      #pragma unroll
      for (int mt = 0; mt < 4; ++mt)
        #pragma unroll
        for (int nt = 0; nt < 2; ++nt)
          acc[mt * 2 + nt] = __builtin_amdgcn_mfma_f32_16x16x32_bf16(af[mt], bfr[nt], acc[mt * 2 + nt], 0, 0, 0);
    }
  }

  if constexpr (MODE == 0) {
    #pragma unroll
    for (int mt = 0; mt < 4; ++mt) {
      int grow0 = m0 + wm + mt * 16 + quad * 4;
      #pragma unroll
      for (int nt = 0; nt < 2; ++nt) {
        int gcol = n0 + wn + nt * 16 + c;
        #pragma unroll
        for (int r = 0; r < 4; ++r)
          C[(size_t)(grow0 + r) * DMODEL + gcol] = acc[mt * 2 + nt][r];
      }
    }
  } else {
    const int whichblk = n0 >> 10;
    if (whichblk == 2) {
      #pragma unroll
      for (int mt = 0; mt < 4; ++mt) {
        int grow0 = m0 + wm + mt * 16 + quad * 4;
        int b = grow0 >> 11, s0 = grow0 & 2047;
        #pragma unroll
        for (int nt = 0; nt < 4; ++nt) {
          int cc = (n0 + wn + nt * 16 + c) & 1023;
          int hh = cc >> 6, dk = cc & 63;
          f32x4_t v4 = acc[mt * 4 + nt];
          ushort4 o;
          o.x = f2b(v4[0]); o.y = f2b(v4[1]); o.z = f2b(v4[2]); o.w = f2b(v4[3]);
          *(ushort4*)(vt16 + (((size_t)(b * NH + hh)) * DK + dk) * S_LEN + s0) = o;
        }
      }
    } else {
      u16* tb = (w & 1) ? Bs : As;
      const int base_mw = m0 + wm;
      const int bb = base_mw >> 11, s0g = base_mw & 2047;
      const int cc = (n0 + wn) & 1023;
      const int hh = cc >> 6;
      u16* qk = (whichblk == 0 ? q16 : k16) + (((size_t)(bb * NH + hh)) * S_LEN + s0g) * DK;
      __syncthreads();   // all frag reads of As/Bs complete
      #pragma unroll
      for (int round = 0; round < 2; ++round) {
        if ((w >> 1) == round) {
          #pragma unroll
          for (int mt = 0; mt < 4; ++mt)
            #pragma unroll
            for (int nt = 0; nt < 4; ++nt)
              #pragma unroll
              for (int r = 0; r < 4; ++r)
                tb[(mt * 16 + quad * 4 + r) * 72 + nt * 16 + c] = f2b(acc[mt * 4 + nt][r]);
          #pragma unroll
          for (int i = 0; i < 8; ++i) {
            int lrow = i * 8 + (l >> 3);
            int chk = l & 7;
            uint4 vv = *(const uint4*)(tb + lrow * 72 + chk * 8);
            *(uint4*)(qk + (size_t)lrow * DK + chk * 8) = vv;
          }
        }
        __syncthreads();
      }
    }
  }
}

// ---------------- MFMA flash attention (R5-proven, ~52 us): 128-q blocks, KVBLK=128, XCD swizzle ----------------
// 512 threads = 8 waves = 4 q-groups (32 q) x 2 key-halves (64 keys = 2 x 32-key chunks).
// Achieved occupancy is invariant at ~32% for 16- and 32-wave/CU caps (R5/R7 evidence) -> this
// configuration is the empirical optimum of the structure family; do not re-trade staging for TLP.
#define KSTR 72    // K row stride in u16 (144 B), R3-proven conflict-free
#define VSTR 136   // V^T row stride in u16 (272 B), same %32-word class as KSTR
__global__ __launch_bounds__(512, 4) void attn_mfma_kernel(const u16* __restrict__ q,
                                                           const u16* __restrict__ k,
                                                           const u16* __restrict__ vt,
                                                           const float* __restrict__ btab,
                                                           u16* __restrict__ ctx) {
  __shared__ __align__(16) char smem[37376];
  u16*   Ks   = (u16*)smem;                   // [128][KSTR]  18432 B
  u16*   Vts  = (u16*)(smem + 18432);         // [64][VSTR]   17408 B
  float* band = (float*)(smem + 35840);       // [256]         1024 B
  float* lpx  = (float*)(smem + 36864);       // [4][32]        512 B

  const int t = threadIdx.x;
  const int w = t >> 6, l = t & 63;
  const int c32 = l & 31, h32 = l >> 5;
  const int grp = w >> 1, kh = w & 1;

  // bijective XCD swizzle: orig%8 = XCD (round-robin dispatch) -> contiguous bh-major chunk
  const int orig = blockIdx.x;                 // 0..511
  const int swz = (orig & 7) * 64 + (orig >> 3);
  const int bh = swz >> 4;                     // 0..31
  const int q0 = (swz & 15) * 128;
  const int h = bh & (NH - 1), b = bh >> 4;

  const u16* qb = q + (size_t)bh * S_LEN * DK;
  const u16* kb = k + (size_t)bh * S_LEN * DK;
  const u16* vb = vt + (size_t)bh * DK * S_LEN;
  const float* btp = btab + h * 4095 + (2047 - 127 - q0);

  // Q fragments (B operand of 32x32x16): lane holds Q[q = c32][dk = kb4*16 + h32*8 + j]
  bf16x8_t qfrag[4];
  {
    const u16* qp = qb + (size_t)(q0 + grp * 32 + c32) * DK + h32 * 8;
    qfrag[0] = *(const bf16x8_t*)(qp);
    qfrag[1] = *(const bf16x8_t*)(qp + 16);
    qfrag[2] = *(const bf16x8_t*)(qp + 32);
    qfrag[3] = *(const bf16x8_t*)(qp + 48);
  }

  float lp = 0.f;
  f32x16_t O0 = {}, O1 = {};   // O: row=q=(r&3)+8*(r>>2)+4*h32, col=dk=dh*32+c32

  // staging (512 threads, 4 x uint4 each): K 128x64, V^T 64x128
  const int ksr = t >> 2;             // 0..127
  const int ksc = (t & 3) * 8;        // 0..24
  const u16* kgp = kb + (size_t)ksr * DK + ksc;
  u16* Kl = Ks + ksr * KSTR + ksc;
  const int vsr = t >> 3;             // 0..63
  const int vsc = (t & 7) * 8;        // 0..56
  const u16* vgp = vb + (size_t)vsr * S_LEN + vsc;
  u16* Vl = Vts + vsr * VSTR + vsc;

  uint4 kr0 = *(const uint4*)kgp;
  uint4 kr1 = *(const uint4*)(kgp + 32);
  uint4 vr0 = *(const uint4*)vgp;
  uint4 vr1 = *(const uint4*)(vgp + 64);
  float br = (t < 256) ? btp[t] : 0.f;

  const int krA = (kh * 64 + c32) * KSTR + h32 * 8;           // chunk A K-frag base
  const int bndcA = 127 + kh * 64 + 4 * h32 - grp * 32 - c32; // chunk A band base

  for (int kt = 0; kt < S_LEN; kt += 128) {
    *(uint4*)Kl = kr0;        *(uint4*)(Kl + 32) = kr1;
    *(uint4*)Vl = vr0;        *(uint4*)(Vl + 64) = vr1;
    if (t < 256) band[t] = br;
    __syncthreads();
    if (kt + 128 < S_LEN) {
      kr0 = *(const uint4*)(kgp + (size_t)(kt + 128) * DK);
      kr1 = *(const uint4*)(kgp + (size_t)(kt + 128) * DK + 32);
      vr0 = *(const uint4*)(vgp + (kt + 128));
      vr1 = *(const uint4*)(vgp + (kt + 128) + 64);
      br = (t < 256) ? btp[kt + 128 + t] : 0.f;
    }
    const int D = kt - q0;
    const bool far = (D >= 256) || (D <= -256);

    // QK^T (swapped), two independent 32-key chunks
    f32x16_t sA = {}, sB = {};
    __builtin_amdgcn_s_setprio(1);
    #pragma unroll
    for (int kb4 = 0; kb4 < 4; ++kb4) {
      bf16x8_t kfA = *(const bf16x8_t*)(Ks + krA + kb4 * 16);
      sA = __builtin_amdgcn_mfma_f32_32x32x16_bf16(kfA, qfrag[kb4], sA, 0, 0, 0);
    }
    #pragma unroll
    for (int kb4 = 0; kb4 < 4; ++kb4) {
      bf16x8_t kfB = *(const bf16x8_t*)(Ks + krA + 32 * KSTR + kb4 * 16);
      sB = __builtin_amdgcn_mfma_f32_32x32x16_bf16(kfB, qfrag[kb4], sB, 0, 0, 0);
    }
    __builtin_amdgcn_s_setprio(0);

    const float bfc = band[127];

    // ---- chunk A: softmax + pack + PV ----
    {
      float p[16];
      if (far) {
        #pragma unroll
        for (int r = 0; r < 16; ++r)
          p[r] = fexp2(fmaf(sA[r], LOG2E, bfc));
      } else {
        #pragma unroll
        for (int r = 0; r < 16; ++r)
          p[r] = fexp2(fmaf(sA[r], LOG2E, band[bndcA + (r & 3) + 8 * (r >> 2)]));
      }
      #pragma unroll
      for (int r = 0; r < 16; ++r)
        lp += p[r];
      union PW { u32 wds[4]; bf16x8_t v; } pa0, pa1;
      u32 x, y;
      x = cvtpk(p[0], p[1]);   y = cvtpk(p[4], p[5]);   plswap(x, y);
      pa0.wds[0] = x; pa0.wds[2] = y;
      x = cvtpk(p[2], p[3]);   y = cvtpk(p[6], p[7]);   plswap(x, y);
      pa0.wds[1] = x; pa0.wds[3] = y;
      x = cvtpk(p[8], p[9]);   y = cvtpk(p[12], p[13]); plswap(x, y);
      pa1.wds[0] = x; pa1.wds[2] = y;
      x = cvtpk(p[10], p[11]); y = cvtpk(p[14], p[15]); plswap(x, y);
      pa1.wds[1] = x; pa1.wds[3] = y;
      __builtin_amdgcn_s_setprio(1);
      bf16x8_t vf00 = *(const bf16x8_t*)(Vts + (c32)      * VSTR + kh * 64 + h32 * 8);
      bf16x8_t vf01 = *(const bf16x8_t*)(Vts + (32 + c32) * VSTR + kh * 64 + h32 * 8);
      O0 = __builtin_amdgcn_mfma_f32_32x32x16_bf16(pa0.v, vf00, O0, 0, 0, 0);
      O1 = __builtin_amdgcn_mfma_f32_32x32x16_bf16(pa0.v, vf01, O1, 0, 0, 0);
      bf16x8_t vf10 = *(const bf16x8_t*)(Vts + (c32)      * VSTR + kh * 64 + 16 + h32 * 8);
      bf16x8_t vf11 = *(const bf16x8_t*)(Vts + (32 + c32) * VSTR + kh * 64 + 16 + h32 * 8);
      O0 = __builtin_amdgcn_mfma_f32_32x32x16_bf16(pa1.v, vf10, O0, 0, 0, 0);
      O1 = __builtin_amdgcn_mfma_f32_32x32x16_bf16(pa1.v, vf11, O1, 0, 0, 0);
      __builtin_amdgcn_s_setprio(0);
    }

    // ---- chunk B (keys +32): softmax + pack + PV ----
    {
      float p[16];
      if (far) {
        #pragma unroll
        for (int r = 0; r < 16; ++r)
          p[r] = fexp2(fmaf(sB[r], LOG2E, bfc));
      } else {
        #pragma unroll
        for (int r = 0; r < 16; ++r)
          p[r] = fexp2(fmaf(sB[r], LOG2E, band[bndcA + 32 + (r & 3) + 8 * (r >> 2)]));
      }
      #pragma unroll
      for (int r = 0; r < 16; ++r)
        lp += p[r];
      union PW { u32 wds[4]; bf16x8_t v; } pa0, pa1;
      u32 x, y;
      x = cvtpk(p[0], p[1]);   y = cvtpk(p[4], p[5]);   plswap(x, y);
      pa0.wds[0] = x; pa0.wds[2] = y;
      x = cvtpk(p[2], p[3]);   y = cvtpk(p[6], p[7]);   plswap(x, y);
      pa0.wds[1] = x; pa0.wds[3] = y;
      x = cvtpk(p[8], p[9]);   y = cvtpk(p[12], p[13]); plswap(x, y);
      pa1.wds[0] = x; pa1.wds[2] = y;
      x = cvtpk(p[10], p[11]); y = cvtpk(p[14], p[15]); plswap(x, y);
      pa1.wds[1] = x; pa1.wds[3] = y;
      __builtin_amdgcn_s_setprio(1);
      bf16x8_t vf00 = *(const bf16x8_t*)(Vts + (c32)      * VSTR + kh * 64 + 32 + h32 * 8);
      bf16x8_t vf01 = *(const bf16x8_t*)(Vts + (32 + c32) * VSTR + kh * 64 + 32 + h32 * 8);
      O0 = __builtin_amdgcn_mfma_f32_32x32x16_bf16(pa0.v, vf00, O0, 0, 0, 0);
      O1 = __builtin_amdgcn_mfma_f32_32x32x16_bf16(pa0.v, vf01, O1, 0, 0, 0);
      bf16x8_t vf10 = *(const bf16x8_t*)(Vts + (c32)      * VSTR + kh * 64 + 48 + h32 * 8);
      bf16x8_t vf11 = *(const bf16x8_t*)(Vts + (32 + c32) * VSTR + kh * 64 + 48 + h32 * 8);
      O0 = __builtin_amdgcn_mfma_f32_32x32x16_bf16(pa1.v, vf10, O0, 0, 0, 0);
      O1 = __builtin_amdgcn_mfma_f32_32x32x16_bf16(pa1.v, vf11, O1, 0, 0, 0);
      __builtin_amdgcn_s_setprio(0);
    }
    __syncthreads();   // all reads of Ks/Vts/band done before next iter's writes
  }

  // ---- epilogue: combine key-half partials; Ored aliases dead Ks/Vts region (33792 <= 35840 B) ----
  lp += __shfl_xor(lp, 32, 64);
  float (*Ored)[64][33] = (float (*)[64][33])smem;

  if (kh == 1) {
    #pragma unroll
    for (int r = 0; r < 16; ++r) {
      Ored[grp][l][r]      = O0[r];
      Ored[grp][l][16 + r] = O1[r];
    }
    if (l < 32) lpx[grp * 32 + l] = lp;
  }
  __syncthreads();
  if (kh == 0) {
    lp += lpx[grp * 32 + c32];
    float rv = 1.0f / lp;            // valid in every lane for q = c32
    #pragma unroll
    for (int r = 0; r < 16; ++r) {
      int qr = (r & 3) + 8 * (r >> 2) + 4 * h32;     // q within group
      float inv = __shfl(rv, qr, 64);
      float o0 = O0[r] + Ored[grp][l][r];
      float o1 = O1[r] + Ored[grp][l][16 + r];
      int s = q0 + grp * 32 + qr;
      u16* cp = ctx + ((size_t)(b * S_LEN + s)) * DMODEL + h * DK;
      cp[c32]      = f2b(o0 * inv);
      cp[32 + c32] = f2b(o1 * inv);
    }
  }
}

extern "C" void kernel_launch(void* const* d_in, const int* in_sizes, int n_in,
                              void* d_out, int out_size, void* d_ws, size_t ws_size,
                              hipStream_t stream) {
  const float* x   = (const float*)d_in[0];
  const float* Wq  = (const float*)d_in[1];
  const float* Wk  = (const float*)d_in[2];
  const float* Wv  = (const float*)d_in[3];
  const float* Wo  = (const float*)d_in[4];
  const float* rel = (const float*)d_in[5];
  float* out = (float*)d_out;

  char* ws = (char*)d_ws;
  size_t off = 0;
  auto carve = [&](size_t bytes) -> char* {
    char* p = ws + off;
    off += (bytes + 255) & ~(size_t)255;
    return p;
  };
  u16*   xb   = (u16*)  carve((size_t)MROWS * DMODEL * 2);       // x bf16
  u16*   Wall = (u16*)  carve((size_t)3 * DMODEL * DMODEL * 2);  // [Wq^T;Wk^T;Wv^T] bf16 [3072][1024]
  u16*   Wto  = (u16*)  carve((size_t)DMODEL * DMODEL * 2);
  u16*   qb16 = (u16*)  carve((size_t)4194304 * 2);              // [bh][s][64] bf16
  u16*   kb16 = (u16*)  carve((size_t)4194304 * 2);
  u16*   vt16 = (u16*)  carve((size_t)4194304 * 2);              // [bh][64][s] bf16
  float* btab = (float*)carve(((size_t)NH * 4095 + 256) * 4);    // +tail slack (band stage)
  u16*   ctxb = (u16*)  carve((size_t)4194304 * 2);              // [b][s][1024] bf16

  prep_kernel<<<8448, 256, 0, stream>>>(x, Wq, Wk, Wv, Wo, rel, xb, Wall, Wto, btab);

  dim3 qkvgrid(32, 24);  // M/128, 3072/128
  gemm128_kernel<1><<<qkvgrid, 256, 0, stream>>>(xb, Wall, nullptr, qb16, kb16, vt16);

  attn_mfma_kernel<<<512, 512, 0, stream>>>(qb16, kb16, vt16, btab, ctxb);

  dim3 ogrid(32, 16);    // M/128, 1024/64
  gemm128_kernel<0><<<ogrid, 256, 0, stream>>>(ctxb, Wto, out, nullptr, nullptr, nullptr);
}

// Round 10
// 190.966 us; speedup vs baseline: 1.0217x; 1.0217x over previous
//
#include <hip/hip_runtime.h>
#include <math.h>

typedef unsigned short u16;
typedef unsigned int u32;
typedef __attribute__((ext_vector_type(8))) short bf16x8_t;
typedef __attribute__((ext_vector_type(4))) float f32x4_t;
typedef __attribute__((ext_vector_type(16))) float f32x16_t;

#define S_LEN  2048
#define NH     16
#define DK     64
#define DMODEL 1024
#define MROWS  4096   // B*S
#define LOG2E  1.44269504088896f

__device__ inline u16 f2b(float f) {
  union { float f; u32 u; } c; c.f = f;
  u32 u = c.u;
  return (u16)((u + 0x7fffu + ((u >> 16) & 1u)) >> 16);  // RNE bf16
}

__device__ __forceinline__ float fexp2(float x) {
#if __has_builtin(__builtin_amdgcn_exp2f)
  return __builtin_amdgcn_exp2f(x);
#else
  return exp2f(x);
#endif
}

__device__ __forceinline__ u32 cvtpk(float lo, float hi) {
  u32 r;
  asm("v_cvt_pk_bf16_f32 %0, %1, %2" : "=v"(r) : "v"(lo), "v"(hi));
  return r;
}

// swap x's high-32-lane half with y's low-32-lane half (gfx950 v_permlane32_swap_b32)
__device__ __forceinline__ void plswap(u32 &x, u32 &y) {
  asm("v_permlane32_swap_b32 %0, %1" : "+v"(x), "+v"(y));
}

// ---------------- global -> LDS DMA: wave-uniform LDS base, lane deposits 16B at base + lane*16 ----------------
__device__ __forceinline__ void stage16(const u16* gp_lane, u16* lds_base) {
#if __has_builtin(__builtin_amdgcn_global_load_lds)
  __builtin_amdgcn_global_load_lds((const __attribute__((address_space(1))) u32*)gp_lane,
                                   (__attribute__((address_space(3))) u32*)lds_base, 16, 0, 0);
#else
  *(uint4*)(lds_base + (threadIdx.x & 63) * 8) = *(const uint4*)gp_lane;
#endif
}

// ---------------- fused prep: cast x, transpose+cast 4 weights, bias table ----------------
__global__ void prep_kernel(const float* __restrict__ x,
                            const float* __restrict__ Wq, const float* __restrict__ Wk,
                            const float* __restrict__ Wv, const float* __restrict__ Wo,
                            const float* __restrict__ rel,
                            u16* __restrict__ xb, u16* __restrict__ Wall,
                            u16* __restrict__ Wto, float* __restrict__ btab) {
  __shared__ float tile[32][33];
  const int bid = blockIdx.x, t = threadIdx.x;
  if (bid < 4096) {
    int i = (bid * 256 + t) * 4;
    float4 v = *(const float4*)(x + i);
    ushort4 o;
    o.x = f2b(v.x); o.y = f2b(v.y); o.z = f2b(v.z); o.w = f2b(v.w);
    *(ushort4*)(xb + i) = o;
  } else if (bid < 8192) {
    int bid2 = bid - 4096;
    int z = bid2 >> 10, rem = bid2 & 1023;
    const float* W; u16* Wt;
    switch (z) {
      case 0: W = Wq; Wt = Wall; break;
      case 1: W = Wk; Wt = Wall + (size_t)DMODEL * DMODEL; break;
      case 2: W = Wv; Wt = Wall + (size_t)2 * DMODEL * DMODEL; break;
      default: W = Wo; Wt = Wto; break;
    }
    int bc = (rem & 31) * 32, br = (rem >> 5) * 32;
    int tx = t & 31, ty = t >> 5;
    #pragma unroll
    for (int yy = 0; yy < 32; yy += 8)
      tile[ty + yy][tx] = W[(size_t)(br + ty + yy) * DMODEL + bc + tx];
    __syncthreads();
    #pragma unroll
    for (int yy = 0; yy < 32; yy += 8)
      Wt[(size_t)(bc + ty + yy) * DMODEL + br + tx] = f2b(tile[tx][ty + yy]);
  } else {
    // bias table: btab[h][delta+2047] = (bias(h,delta) - 16) * log2(e)   [exp2-domain]
    int idx = (bid - 8192) * 256 + t;
    if (idx < NH * 4095) {
      int h = idx / 4095;
      int dpos = idx - h * 4095;
      int delta = dpos - 2047;               // j - i; reference n = i - j
      int ret = (delta > 0) ? 16 : 0;
      int n = delta < 0 ? -delta : delta;
      int bucket;
      if (n < 8) {
        bucket = ret + n;
      } else {
        float vf = logf((float)n * 0.125f) / 2.7725887222397811f * 8.0f;
        int vil = 8 + (int)vf;
        bucket = ret + (vil < 15 ? vil : 15);
      }
      btab[idx] = (rel[bucket * NH + h] - 16.0f) * LOG2E;
    }
  }
}

// ---------------- bf16 MFMA GEMM ----------------
// MODE 1: fused QKV, 128x128 tile, BK=64 with XOR-swizzled LDS (R10). R9's linear [128][64] had a
//         128B row stride -> 8x ds_read_b128 serialization (9.5M conflicts). Fix per rule #21:
//         LDS cell (r,g) holds global chunk g^(r&7); write side pre-swizzles the GLOBAL source
//         (dest stays linear for global_load_lds), read side XORs the chunk index. Bank math:
//         granule (kc*4+quad)^(c&7) -> exactly 8 dwords/bank = conflict-free minimum.
//         Keeps BK=64's halved barrier count (16 drains vs 32).
// MODE 0: out-projection, 128x64 tile, grid (32,16)=512 blocks=2/CU; manual staging + register
//         prefetch (R8-proven, -5 us vs 128x128 @ 1/CU).
#define GSTR 56   // manual-path LDS row stride (112 B): 16B-aligned, 2-way bank aliasing (free)
template <int MODE>
__global__ __launch_bounds__(256) void gemm128_kernel(const u16* __restrict__ A,
                                                      const u16* __restrict__ Bt,
                                                      float* __restrict__ C,
                                                      u16* __restrict__ q16,
                                                      u16* __restrict__ k16,
                                                      u16* __restrict__ vt16) {
  constexpr int ABSZ = (MODE == 1) ? 8192 : 128 * GSTR;
  constexpr int BSZ  = (MODE == 1) ? 8192 : 64 * GSTR;
  constexpr int FSTR = (MODE == 1) ? 64 : GSTR;
  __shared__ __align__(16) u16 As[ABSZ];
  __shared__ __align__(16) u16 Bs[BSZ];
  const int t = threadIdx.x, w = t >> 6, l = t & 63;
  const int c = l & 15, quad = l >> 4;
  const int m0 = blockIdx.x * 128;
  const int n0 = blockIdx.y * ((MODE == 1) ? 128 : 64);
  const int wm = (w & 1) * 64;
  const int wn = (w >> 1) * ((MODE == 1) ? 64 : 32);

  f32x4_t acc[16] = {};

  if constexpr (MODE == 1) {
    // BK=64 swizzled DMA map: wave w stages rows w*32..+31 in 4 slabs of 8 rows; lane l deposits
    // 16B linearly at slab row l>>3, chunk l&7 -- but SOURCES global chunk (l&7)^(l>>3) so that
    // LDS cell (r, g) ends up holding global chunk g^(r&7)  (r&7 == l>>3 since m0,w*32,s*8 == 0 mod 8).
    const int sr8 = l >> 3;                    // 0..7
    const int k8s = ((l & 7) ^ sr8) * 8;       // pre-swizzled source col chunk (XOR involution)
    const u16* AgB = A  + (size_t)(m0 + w * 32 + sr8) * DMODEL + k8s;
    const u16* BgB = Bt + (size_t)(n0 + w * 32 + sr8) * DMODEL + k8s;
    u16* Al = As + w * 2048;   // w*32 rows * 64 cols
    u16* Bl = Bs + w * 2048;
    for (int k0 = 0; k0 < DMODEL; k0 += 64) {
      __syncthreads();   // prior frag reads done
      #pragma unroll
      for (int s = 0; s < 4; ++s) {
        stage16(AgB + (size_t)s * 8 * DMODEL + k0, Al + s * 512);
        stage16(BgB + (size_t)s * 8 * DMODEL + k0, Bl + s * 512);
      }
      __syncthreads();   // vmcnt drain before barrier completes staging
      #pragma unroll
      for (int kc = 0; kc < 2; ++kc) {
        const int swzc = ((kc * 4 + quad) ^ (c & 7)) * 8;   // swizzled chunk for this frag read
        bf16x8_t af[4], bfr[4];
        #pragma unroll
        for (int i = 0; i < 4; ++i) {
          af[i]  = *(const bf16x8_t*)(As + (wm + i * 16 + c) * 64 + swzc);
          bfr[i] = *(const bf16x8_t*)(Bs + (wn + i * 16 + c) * 64 + swzc);
        }
        #pragma unroll
        for (int mt = 0; mt < 4; ++mt)
          #pragma unroll
          for (int nt = 0; nt < 4; ++nt)
            acc[mt * 4 + nt] = __builtin_amdgcn_mfma_f32_16x16x32_bf16(af[mt], bfr[nt], acc[mt * 4 + nt], 0, 0, 0);
      }
    }
  } else {
    // manual staging + register prefetch; A: 128x32, B: 64x32 per K-step
    const int sr = t >> 2;              // 0..63
    const int k8 = (t & 3) * 8;
    const u16* Ag0 = A  + (size_t)(m0 + sr) * DMODEL + k8;
    const u16* Ag1 = Ag0 + (size_t)64 * DMODEL;
    const u16* Bg0 = Bt + (size_t)(n0 + sr) * DMODEL + k8;
    u16* Al0 = As + sr * GSTR + k8;
    u16* Al1 = Al0 + 64 * GSTR;
    u16* Bl0 = Bs + sr * GSTR + k8;

    uint4 a0 = *(const uint4*)Ag0, a1 = *(const uint4*)Ag1;
    uint4 b0 = *(const uint4*)Bg0;
    for (int k0 = 0; k0 < DMODEL; k0 += 32) {
      __syncthreads();
      *(uint4*)Al0 = a0; *(uint4*)Al1 = a1;
      *(uint4*)Bl0 = b0;
      __syncthreads();
      if (k0 + 32 < DMODEL) {
        a0 = *(const uint4*)(Ag0 + k0 + 32);
        a1 = *(const uint4*)(Ag1 + k0 + 32);
        b0 = *(const uint4*)(Bg0 + k0 + 32);
      }
      bf16x8_t af[4], bfr[2];
      #pragma unroll
      for (int i = 0; i < 4; ++i)
        af[i] = *(const bf16x8_t*)(As + (wm + i * 16 + c) * FSTR + quad * 8);
      #pragma unroll
      for (int i = 0; i < 2; ++i)
        bfr[i] = *(const bf16x8_t*)(Bs + (wn + i * 16 + c) * FSTR + quad * 8);
      #pragma unroll
      for (int mt = 0; mt < 4; ++mt)
        #pragma unroll
        for (int nt = 0; nt < 2; ++nt)
          acc[mt * 2 + nt] = __builtin_amdgcn_mfma_f32_16x16x32_bf16(af[mt], bfr[nt], acc[mt * 2 + nt], 0, 0, 0);
    }
  }

  if constexpr (MODE == 0) {
    #pragma unroll
    for (int mt = 0; mt < 4; ++mt) {
      int grow0 = m0 + wm + mt * 16 + quad * 4;
      #pragma unroll
      for (int nt = 0; nt < 2; ++nt) {
        int gcol = n0 + wn + nt * 16 + c;
        #pragma unroll
        for (int r = 0; r < 4; ++r)
          C[(size_t)(grow0 + r) * DMODEL + gcol] = acc[mt * 2 + nt][r];
      }
    }
  } else {
    const int whichblk = n0 >> 10;
    if (whichblk == 2) {
      #pragma unroll
      for (int mt = 0; mt < 4; ++mt) {
        int grow0 = m0 + wm + mt * 16 + quad * 4;
        int b = grow0 >> 11, s0 = grow0 & 2047;
        #pragma unroll
        for (int nt = 0; nt < 4; ++nt) {
          int cc = (n0 + wn + nt * 16 + c) & 1023;
          int hh = cc >> 6, dk = cc & 63;
          f32x4_t v4 = acc[mt * 4 + nt];
          ushort4 o;
          o.x = f2b(v4[0]); o.y = f2b(v4[1]); o.z = f2b(v4[2]); o.w = f2b(v4[3]);
          *(ushort4*)(vt16 + (((size_t)(b * NH + hh)) * DK + dk) * S_LEN + s0) = o;
        }
      }
    } else {
      u16* tb = (w & 1) ? Bs : As;
      const int base_mw = m0 + wm;
      const int bb = base_mw >> 11, s0g = base_mw & 2047;
      const int cc = (n0 + wn) & 1023;
      const int hh = cc >> 6;
      u16* qk = (whichblk == 0 ? q16 : k16) + (((size_t)(bb * NH + hh)) * S_LEN + s0g) * DK;
      __syncthreads();   // all frag reads of As/Bs complete
      #pragma unroll
      for (int round = 0; round < 2; ++round) {
        if ((w >> 1) == round) {
          #pragma unroll
          for (int mt = 0; mt < 4; ++mt)
            #pragma unroll
            for (int nt = 0; nt < 4; ++nt)
              #pragma unroll
              for (int r = 0; r < 4; ++r)
                tb[(mt * 16 + quad * 4 + r) * 72 + nt * 16 + c] = f2b(acc[mt * 4 + nt][r]);
          #pragma unroll
          for (int i = 0; i < 8; ++i) {
            int lrow = i * 8 + (l >> 3);
            int chk = l & 7;
            uint4 vv = *(const uint4*)(tb + lrow * 72 + chk * 8);
            *(uint4*)(qk + (size_t)lrow * DK + chk * 8) = vv;
          }
        }
        __syncthreads();
      }
    }
  }
}

// ---------------- MFMA flash attention (R5-proven, ~52 us): 128-q blocks, KVBLK=128, XCD swizzle ----------------
// 512 threads = 8 waves = 4 q-groups (32 q) x 2 key-halves (64 keys = 2 x 32-key chunks).
// Achieved occupancy is invariant at ~32% for 16- and 32-wave/CU caps (R5/R7 evidence) -> this
// configuration is the empirical optimum of the structure family; do not re-trade staging for TLP.
#define KSTR 72    // K row stride in u16 (144 B), R3-proven conflict-free
#define VSTR 136   // V^T row stride in u16 (272 B), same %32-word class as KSTR
__global__ __launch_bounds__(512, 4) void attn_mfma_kernel(const u16* __restrict__ q,
                                                           const u16* __restrict__ k,
                                                           const u16* __restrict__ vt,
                                                           const float* __restrict__ btab,
                                                           u16* __restrict__ ctx) {
  __shared__ __align__(16) char smem[37376];
  u16*   Ks   = (u16*)smem;                   // [128][KSTR]  18432 B
  u16*   Vts  = (u16*)(smem + 18432);         // [64][VSTR]   17408 B
  float* band = (float*)(smem + 35840);       // [256]         1024 B
  float* lpx  = (float*)(smem + 36864);       // [4][32]        512 B

  const int t = threadIdx.x;
  const int w = t >> 6, l = t & 63;
  const int c32 = l & 31, h32 = l >> 5;
  const int grp = w >> 1, kh = w & 1;

  // bijective XCD swizzle: orig%8 = XCD (round-robin dispatch) -> contiguous bh-major chunk
  const int orig = blockIdx.x;                 // 0..511
  const int swz = (orig & 7) * 64 + (orig >> 3);
  const int bh = swz >> 4;                     // 0..31
  const int q0 = (swz & 15) * 128;
  const int h = bh & (NH - 1), b = bh >> 4;

  const u16* qb = q + (size_t)bh * S_LEN * DK;
  const u16* kb = k + (size_t)bh * S_LEN * DK;
  const u16* vb = vt + (size_t)bh * DK * S_LEN;
  const float* btp = btab + h * 4095 + (2047 - 127 - q0);

  // Q fragments (B operand of 32x32x16): lane holds Q[q = c32][dk = kb4*16 + h32*8 + j]
  bf16x8_t qfrag[4];
  {
    const u16* qp = qb + (size_t)(q0 + grp * 32 + c32) * DK + h32 * 8;
    qfrag[0] = *(const bf16x8_t*)(qp);
    qfrag[1] = *(const bf16x8_t*)(qp + 16);
    qfrag[2] = *(const bf16x8_t*)(qp + 32);
    qfrag[3] = *(const bf16x8_t*)(qp + 48);
  }

  float lp = 0.f;
  f32x16_t O0 = {}, O1 = {};   // O: row=q=(r&3)+8*(r>>2)+4*h32, col=dk=dh*32+c32

  // staging (512 threads, 4 x uint4 each): K 128x64, V^T 64x128
  const int ksr = t >> 2;             // 0..127
  const int ksc = (t & 3) * 8;        // 0..24
  const u16* kgp = kb + (size_t)ksr * DK + ksc;
  u16* Kl = Ks + ksr * KSTR + ksc;
  const int vsr = t >> 3;             // 0..63
  const int vsc = (t & 7) * 8;        // 0..56
  const u16* vgp = vb + (size_t)vsr * S_LEN + vsc;
  u16* Vl = Vts + vsr * VSTR + vsc;

  uint4 kr0 = *(const uint4*)kgp;
  uint4 kr1 = *(const uint4*)(kgp + 32);
  uint4 vr0 = *(const uint4*)vgp;
  uint4 vr1 = *(const uint4*)(vgp + 64);
  float br = (t < 256) ? btp[t] : 0.f;

  const int krA = (kh * 64 + c32) * KSTR + h32 * 8;           // chunk A K-frag base
  const int bndcA = 127 + kh * 64 + 4 * h32 - grp * 32 - c32; // chunk A band base

  for (int kt = 0; kt < S_LEN; kt += 128) {
    *(uint4*)Kl = kr0;        *(uint4*)(Kl + 32) = kr1;
    *(uint4*)Vl = vr0;        *(uint4*)(Vl + 64) = vr1;
    if (t < 256) band[t] = br;
    __syncthreads();
    if (kt + 128 < S_LEN) {
      kr0 = *(const uint4*)(kgp + (size_t)(kt + 128) * DK);
      kr1 = *(const uint4*)(kgp + (size_t)(kt + 128) * DK + 32);
      vr0 = *(const uint4*)(vgp + (kt + 128));
      vr1 = *(const uint4*)(vgp + (kt + 128) + 64);
      br = (t < 256) ? btp[kt + 128 + t] : 0.f;
    }
    const int D = kt - q0;
    const bool far = (D >= 256) || (D <= -256);

    // QK^T (swapped), two independent 32-key chunks
    f32x16_t sA = {}, sB = {};
    __builtin_amdgcn_s_setprio(1);
    #pragma unroll
    for (int kb4 = 0; kb4 < 4; ++kb4) {
      bf16x8_t kfA = *(const bf16x8_t*)(Ks + krA + kb4 * 16);
      sA = __builtin_amdgcn_mfma_f32_32x32x16_bf16(kfA, qfrag[kb4], sA, 0, 0, 0);
    }
    #pragma unroll
    for (int kb4 = 0; kb4 < 4; ++kb4) {
      bf16x8_t kfB = *(const bf16x8_t*)(Ks + krA + 32 * KSTR + kb4 * 16);
      sB = __builtin_amdgcn_mfma_f32_32x32x16_bf16(kfB, qfrag[kb4], sB, 0, 0, 0);
    }
    __builtin_amdgcn_s_setprio(0);

    const float bfc = band[127];

    // ---- chunk A: softmax + pack + PV ----
    {
      float p[16];
      if (far) {
        #pragma unroll
        for (int r = 0; r < 16; ++r)
          p[r] = fexp2(fmaf(sA[r], LOG2E, bfc));
      } else {
        #pragma unroll
        for (int r = 0; r < 16; ++r)
          p[r] = fexp2(fmaf(sA[r], LOG2E, band[bndcA + (r & 3) + 8 * (r >> 2)]));
      }
      #pragma unroll
      for (int r = 0; r < 16; ++r)
        lp += p[r];
      union PW { u32 wds[4]; bf16x8_t v; } pa0, pa1;
      u32 x, y;
      x = cvtpk(p[0], p[1]);   y = cvtpk(p[4], p[5]);   plswap(x, y);
      pa0.wds[0] = x; pa0.wds[2] = y;
      x = cvtpk(p[2], p[3]);   y = cvtpk(p[6], p[7]);   plswap(x, y);
      pa0.wds[1] = x; pa0.wds[3] = y;
      x = cvtpk(p[8], p[9]);   y = cvtpk(p[12], p[13]); plswap(x, y);
      pa1.wds[0] = x; pa1.wds[2] = y;
      x = cvtpk(p[10], p[11]); y = cvtpk(p[14], p[15]); plswap(x, y);
      pa1.wds[1] = x; pa1.wds[3] = y;
      __builtin_amdgcn_s_setprio(1);
      bf16x8_t vf00 = *(const bf16x8_t*)(Vts + (c32)      * VSTR + kh * 64 + h32 * 8);
      bf16x8_t vf01 = *(const bf16x8_t*)(Vts + (32 + c32) * VSTR + kh * 64 + h32 * 8);
      O0 = __builtin_amdgcn_mfma_f32_32x32x16_bf16(pa0.v, vf00, O0, 0, 0, 0);
      O1 = __builtin_amdgcn_mfma_f32_32x32x16_bf16(pa0.v, vf01, O1, 0, 0, 0);
      bf16x8_t vf10 = *(const bf16x8_t*)(Vts + (c32)      * VSTR + kh * 64 + 16 + h32 * 8);
      bf16x8_t vf11 = *(const bf16x8_t*)(Vts + (32 + c32) * VSTR + kh * 64 + 16 + h32 * 8);
      O0 = __builtin_amdgcn_mfma_f32_32x32x16_bf16(pa1.v, vf10, O0, 0, 0, 0);
      O1 = __builtin_amdgcn_mfma_f32_32x32x16_bf16(pa1.v, vf11, O1, 0, 0, 0);
      __builtin_amdgcn_s_setprio(0);
    }

    // ---- chunk B (keys +32): softmax + pack + PV ----
    {
      float p[16];
      if (far) {
        #pragma unroll
        for (int r = 0; r < 16; ++r)
          p[r] = fexp2(fmaf(sB[r], LOG2E, bfc));
      } else {
        #pragma unroll
        for (int r = 0; r < 16; ++r)
          p[r] = fexp2(fmaf(sB[r], LOG2E, band[bndcA + 32 + (r & 3) + 8 * (r >> 2)]));
      }
      #pragma unroll
      for (int r = 0; r < 16; ++r)
        lp += p[r];
      union PW { u32 wds[4]; bf16x8_t v; } pa0, pa1;
      u32 x, y;
      x = cvtpk(p[0], p[1]);   y = cvtpk(p[4], p[5]);   plswap(x, y);
      pa0.wds[0] = x; pa0.wds[2] = y;
      x = cvtpk(p[2], p[3]);   y = cvtpk(p[6], p[7]);   plswap(x, y);
      pa0.wds[1] = x; pa0.wds[3] = y;
      x = cvtpk(p[8], p[9]);   y = cvtpk(p[12], p[13]); plswap(x, y);
      pa1.wds[0] = x; pa1.wds[2] = y;
      x = cvtpk(p[10], p[11]); y = cvtpk(p[14], p[15]); plswap(x, y);
      pa1.wds[1] = x; pa1.wds[3] = y;
      __builtin_amdgcn_s_setprio(1);
      bf16x8_t vf00 = *(const bf16x8_t*)(Vts + (c32)      * VSTR + kh * 64 + 32 + h32 * 8);
      bf16x8_t vf01 = *(const bf16x8_t*)(Vts + (32 + c32) * VSTR + kh * 64 + 32 + h32 * 8);
      O0 = __builtin_amdgcn_mfma_f32_32x32x16_bf16(pa0.v, vf00, O0, 0, 0, 0);
      O1 = __builtin_amdgcn_mfma_f32_32x32x16_bf16(pa0.v, vf01, O1, 0, 0, 0);
      bf16x8_t vf10 = *(const bf16x8_t*)(Vts + (c32)      * VSTR + kh * 64 + 48 + h32 * 8);
      bf16x8_t vf11 = *(const bf16x8_t*)(Vts + (32 + c32) * VSTR + kh * 64 + 48 + h32 * 8);
      O0 = __builtin_amdgcn_mfma_f32_32x32x16_bf16(pa1.v, vf10, O0, 0, 0, 0);
      O1 = __builtin_amdgcn_mfma_f32_32x32x16_bf16(pa1.v, vf11, O1, 0, 0, 0);
      __builtin_amdgcn_s_setprio(0);
    }
    __syncthreads();   // all reads of Ks/Vts/band done before next iter's writes
  }

  // ---- epilogue: combine key-half partials; Ored aliases dead Ks/Vts region (33792 <= 35840 B) ----
  lp += __shfl_xor(lp, 32, 64);
  float (*Ored)[64][33] = (float (*)[64][33])smem;

  if (kh == 1) {
    #pragma unroll
    for (int r = 0; r < 16; ++r) {
      Ored[grp][l][r]      = O0[r];
      Ored[grp][l][16 + r] = O1[r];
    }
    if (l < 32) lpx[grp * 32 + l] = lp;
  }
  __syncthreads();
  if (kh == 0) {
    lp += lpx[grp * 32 + c32];
    float rv = 1.0f / lp;            // valid in every lane for q = c32
    #pragma unroll
    for (int r = 0; r < 16; ++r) {
      int qr = (r & 3) + 8 * (r >> 2) + 4 * h32;     // q within group
      float inv = __shfl(rv, qr, 64);
      float o0 = O0[r] + Ored[grp][l][r];
      float o1 = O1[r] + Ored[grp][l][16 + r];
      int s = q0 + grp * 32 + qr;
      u16* cp = ctx + ((size_t)(b * S_LEN + s)) * DMODEL + h * DK;
      cp[c32]      = f2b(o0 * inv);
      cp[32 + c32] = f2b(o1 * inv);
    }
  }
}

extern "C" void kernel_launch(void* const* d_in, const int* in_sizes, int n_in,
                              void* d_out, int out_size, void* d_ws, size_t ws_size,
                              hipStream_t stream) {
  const float* x   = (const float*)d_in[0];
  const float* Wq  = (const float*)d_in[1];
  const float* Wk  = (const float*)d_in[2];
  const float* Wv  = (const float*)d_in[3];
  const float* Wo  = (const float*)d_in[4];
  const float* rel = (const float*)d_in[5];
  float* out = (float*)d_out;

  char* ws = (char*)d_ws;
  size_t off = 0;
  auto carve = [&](size_t bytes) -> char* {
    char* p = ws + off;
    off += (bytes + 255) & ~(size_t)255;
    return p;
  };
  u16*   xb   = (u16*)  carve((size_t)MROWS * DMODEL * 2);       // x bf16
  u16*   Wall = (u16*)  carve((size_t)3 * DMODEL * DMODEL * 2);  // [Wq^T;Wk^T;Wv^T] bf16 [3072][1024]
  u16*   Wto  = (u16*)  carve((size_t)DMODEL * DMODEL * 2);
  u16*   qb16 = (u16*)  carve((size_t)4194304 * 2);              // [bh][s][64] bf16
  u16*   kb16 = (u16*)  carve((size_t)4194304 * 2);
  u16*   vt16 = (u16*)  carve((size_t)4194304 * 2);              // [bh][64][s] bf16
  float* btab = (float*)carve(((size_t)NH * 4095 + 256) * 4);    // +tail slack (band stage)
  u16*   ctxb = (u16*)  carve((size_t)4194304 * 2);              // [b][s][1024] bf16

  prep_kernel<<<8448, 256, 0, stream>>>(x, Wq, Wk, Wv, Wo, rel, xb, Wall, Wto, btab);

  dim3 qkvgrid(32, 24);  // M/128, 3072/128
  gemm128_kernel<1><<<qkvgrid, 256, 0, stream>>>(xb, Wall, nullptr, qb16, kb16, vt16);

  attn_mfma_kernel<<<512, 512, 0, stream>>>(qb16, kb16, vt16, btab, ctxb);

  dim3 ogrid(32, 16);    // M/128, 1024/64
  gemm128_kernel<0><<<ogrid, 256, 0, stream>>>(ctxb, Wto, out, nullptr, nullptr, nullptr);
}

// Round 11
// 183.070 us; speedup vs baseline: 1.0658x; 1.0431x over previous
//
#include <hip/hip_runtime.h>
#include <math.h>

typedef unsigned short u16;
typedef unsigned int u32;
typedef __attribute__((ext_vector_type(8))) short bf16x8_t;
typedef __attribute__((ext_vector_type(4))) float f32x4_t;
typedef __attribute__((ext_vector_type(16))) float f32x16_t;

#define S_LEN  2048
#define NH     16
#define DK     64
#define DMODEL 1024
#define MROWS  4096   // B*S
#define LOG2E  1.44269504088896f

__device__ inline u16 f2b(float f) {
  union { float f; u32 u; } c; c.f = f;
  u32 u = c.u;
  return (u16)((u + 0x7fffu + ((u >> 16) & 1u)) >> 16);  // RNE bf16
}

__device__ __forceinline__ float fexp2(float x) {
#if __has_builtin(__builtin_amdgcn_exp2f)
  return __builtin_amdgcn_exp2f(x);
#else
  return exp2f(x);
#endif
}

__device__ __forceinline__ u32 cvtpk(float lo, float hi) {
  u32 r;
  asm("v_cvt_pk_bf16_f32 %0, %1, %2" : "=v"(r) : "v"(lo), "v"(hi));
  return r;
}

// swap x's high-32-lane half with y's low-32-lane half (gfx950 v_permlane32_swap_b32)
__device__ __forceinline__ void plswap(u32 &x, u32 &y) {
  asm("v_permlane32_swap_b32 %0, %1" : "+v"(x), "+v"(y));
}

// ---------------- global -> LDS DMA: wave-uniform LDS base, lane deposits 16B at base + lane*16 ----------------
__device__ __forceinline__ void stage16(const u16* gp_lane, u16* lds_base) {
#if __has_builtin(__builtin_amdgcn_global_load_lds)
  __builtin_amdgcn_global_load_lds((const __attribute__((address_space(1))) u32*)gp_lane,
                                   (__attribute__((address_space(3))) u32*)lds_base, 16, 0, 0);
#else
  *(uint4*)(lds_base + (threadIdx.x & 63) * 8) = *(const uint4*)gp_lane;
#endif
}

// ---------------- fused prep: cast x, transpose+cast 4 weights, bias table ----------------
__global__ void prep_kernel(const float* __restrict__ x,
                            const float* __restrict__ Wq, const float* __restrict__ Wk,
                            const float* __restrict__ Wv, const float* __restrict__ Wo,
                            const float* __restrict__ rel,
                            u16* __restrict__ xb, u16* __restrict__ Wall,
                            u16* __restrict__ Wto, float* __restrict__ btab) {
  __shared__ float tile[32][33];
  const int bid = blockIdx.x, t = threadIdx.x;
  if (bid < 4096) {
    int i = (bid * 256 + t) * 4;
    float4 v = *(const float4*)(x + i);
    ushort4 o;
    o.x = f2b(v.x); o.y = f2b(v.y); o.z = f2b(v.z); o.w = f2b(v.w);
    *(ushort4*)(xb + i) = o;
  } else if (bid < 8192) {
    int bid2 = bid - 4096;
    int z = bid2 >> 10, rem = bid2 & 1023;
    const float* W; u16* Wt;
    switch (z) {
      case 0: W = Wq; Wt = Wall; break;
      case 1: W = Wk; Wt = Wall + (size_t)DMODEL * DMODEL; break;
      case 2: W = Wv; Wt = Wall + (size_t)2 * DMODEL * DMODEL; break;
      default: W = Wo; Wt = Wto; break;
    }
    int bc = (rem & 31) * 32, br = (rem >> 5) * 32;
    int tx = t & 31, ty = t >> 5;
    #pragma unroll
    for (int yy = 0; yy < 32; yy += 8)
      tile[ty + yy][tx] = W[(size_t)(br + ty + yy) * DMODEL + bc + tx];
    __syncthreads();
    #pragma unroll
    for (int yy = 0; yy < 32; yy += 8)
      Wt[(size_t)(bc + ty + yy) * DMODEL + br + tx] = f2b(tile[tx][ty + yy]);
  } else {
    // bias table: btab[h][delta+2047] = (bias(h,delta) - 16) * log2(e)   [exp2-domain]
    int idx = (bid - 8192) * 256 + t;
    if (idx < NH * 4095) {
      int h = idx / 4095;
      int dpos = idx - h * 4095;
      int delta = dpos - 2047;               // j - i; reference n = i - j
      int ret = (delta > 0) ? 16 : 0;
      int n = delta < 0 ? -delta : delta;
      int bucket;
      if (n < 8) {
        bucket = ret + n;
      } else {
        float vf = logf((float)n * 0.125f) / 2.7725887222397811f * 8.0f;
        int vil = 8 + (int)vf;
        bucket = ret + (vil < 15 ? vil : 15);
      }
      btab[idx] = (rel[bucket * NH + h] - 16.0f) * LOG2E;
    }
  }
}

// ---------------- bf16 MFMA GEMM ----------------
// MODE 1: fused QKV, 128x128 tile, BK=32 (R8-proven conflict-free [128][32] layout) with R11's
//         T3-minimum 2-phase double buffer: STAGE(t+1 -> buf^1) issued BEFORE compute(t), single
//         __syncthreads (incl. vmcnt drain) per K-step. Loads get the full frag-read+MFMA phase
//         (~250 cyc) to land instead of draining immediately; barriers 64 -> 33 per block.
//         LDS 2x[128][32] per matrix = 32 KB; grid (32,24)=768 blocks stays 3 blocks/CU (96 KB).
//         (BK=64 tried in R9/R10: linear = 9.5M bank conflicts; swizzled = fixed conflicts but
//         still net -11 us vs BK=32 -- longer per-iteration drain loses at K=1024. Reverted.)
// MODE 0: out-projection, 128x64 tile, grid (32,16)=512 blocks=2/CU; manual staging + register
//         prefetch (R8-proven, -5 us vs 128x128 @ 1/CU).
#define GSTR 56   // manual-path LDS row stride (112 B): 16B-aligned, 2-way bank aliasing (free)
template <int MODE>
__global__ __launch_bounds__(256) void gemm128_kernel(const u16* __restrict__ A,
                                                      const u16* __restrict__ Bt,
                                                      float* __restrict__ C,
                                                      u16* __restrict__ q16,
                                                      u16* __restrict__ k16,
                                                      u16* __restrict__ vt16) {
  constexpr int ABSZ = (MODE == 1) ? 8192 : 128 * GSTR;   // MODE 1: 2 dbuf x 4096 u16
  constexpr int BSZ  = (MODE == 1) ? 8192 : 64 * GSTR;
  constexpr int FSTR = (MODE == 1) ? 32 : GSTR;
  __shared__ __align__(16) u16 As[ABSZ];
  __shared__ __align__(16) u16 Bs[BSZ];
  const int t = threadIdx.x, w = t >> 6, l = t & 63;
  const int c = l & 15, quad = l >> 4;
  const int m0 = blockIdx.x * 128;
  const int n0 = blockIdx.y * ((MODE == 1) ? 128 : 64);
  const int wm = (w & 1) * 64;
  const int wn = (w >> 1) * ((MODE == 1) ? 64 : 32);

  f32x4_t acc[16] = {};

  if constexpr (MODE == 1) {
    // R8 DMA map: wave w stages rows w*32..+31 (two 16-row slabs); lane l -> row l>>2, chunk l&3
    const int sr = l >> 2;
    const int k8 = (l & 3) * 8;
    const u16* Ag0 = A  + (size_t)(m0 + w * 32 + sr) * DMODEL + k8;
    const u16* Ag1 = Ag0 + (size_t)16 * DMODEL;
    const u16* Bg0 = Bt + (size_t)(n0 + w * 32 + sr) * DMODEL + k8;
    const u16* Bg1 = Bg0 + (size_t)16 * DMODEL;

    // prologue: tile 0 -> buf 0, drain, barrier
    {
      u16* Al = As + w * 1024;
      u16* Bl = Bs + w * 1024;
      stage16(Ag0, Al);
      stage16(Ag1, Al + 512);
      stage16(Bg0, Bl);
      stage16(Bg1, Bl + 512);
    }
    __syncthreads();   // vmcnt(0) drain: tile 0 resident

    int cur = 0;
    for (int k0 = 0; k0 < DMODEL; k0 += 32) {
      // 1. issue next tile's loads into the alternate buffer (async, lands during compute)
      if (k0 + 32 < DMODEL) {
        u16* Aln = As + (cur ^ 1) * 4096 + w * 1024;
        u16* Bln = Bs + (cur ^ 1) * 4096 + w * 1024;
        stage16(Ag0 + k0 + 32, Aln);
        stage16(Ag1 + k0 + 32, Aln + 512);
        stage16(Bg0 + k0 + 32, Bln);
        stage16(Bg1 + k0 + 32, Bln + 512);
      }
      // 2. compute current tile
      const u16* Ac = As + cur * 4096;
      const u16* Bc = Bs + cur * 4096;
      bf16x8_t af[4], bfr[4];
      #pragma unroll
      for (int i = 0; i < 4; ++i) {
        af[i]  = *(const bf16x8_t*)(Ac + (wm + i * 16 + c) * 32 + quad * 8);
        bfr[i] = *(const bf16x8_t*)(Bc + (wn + i * 16 + c) * 32 + quad * 8);
      }
      #pragma unroll
      for (int mt = 0; mt < 4; ++mt)
        #pragma unroll
        for (int nt = 0; nt < 4; ++nt)
          acc[mt * 4 + nt] = __builtin_amdgcn_mfma_f32_16x16x32_bf16(af[mt], bfr[nt], acc[mt * 4 + nt], 0, 0, 0);
      // 3. one barrier per K-step: drains next-tile loads AND protects buf[cur] from overwrite
      __syncthreads();
      cur ^= 1;
    }
  } else {
    // manual staging + register prefetch; A: 128x32, B: 64x32 per K-step
    const int sr = t >> 2;              // 0..63
    const int k8 = (t & 3) * 8;
    const u16* Ag0 = A  + (size_t)(m0 + sr) * DMODEL + k8;
    const u16* Ag1 = Ag0 + (size_t)64 * DMODEL;
    const u16* Bg0 = Bt + (size_t)(n0 + sr) * DMODEL + k8;
    u16* Al0 = As + sr * GSTR + k8;
    u16* Al1 = Al0 + 64 * GSTR;
    u16* Bl0 = Bs + sr * GSTR + k8;

    uint4 a0 = *(const uint4*)Ag0, a1 = *(const uint4*)Ag1;
    uint4 b0 = *(const uint4*)Bg0;
    for (int k0 = 0; k0 < DMODEL; k0 += 32) {
      __syncthreads();
      *(uint4*)Al0 = a0; *(uint4*)Al1 = a1;
      *(uint4*)Bl0 = b0;
      __syncthreads();
      if (k0 + 32 < DMODEL) {
        a0 = *(const uint4*)(Ag0 + k0 + 32);
        a1 = *(const uint4*)(Ag1 + k0 + 32);
        b0 = *(const uint4*)(Bg0 + k0 + 32);
      }
      bf16x8_t af[4], bfr[2];
      #pragma unroll
      for (int i = 0; i < 4; ++i)
        af[i] = *(const bf16x8_t*)(As + (wm + i * 16 + c) * FSTR + quad * 8);
      #pragma unroll
      for (int i = 0; i < 2; ++i)
        bfr[i] = *(const bf16x8_t*)(Bs + (wn + i * 16 + c) * FSTR + quad * 8);
      #pragma unroll
      for (int mt = 0; mt < 4; ++mt)
        #pragma unroll
        for (int nt = 0; nt < 2; ++nt)
          acc[mt * 2 + nt] = __builtin_amdgcn_mfma_f32_16x16x32_bf16(af[mt], bfr[nt], acc[mt * 2 + nt], 0, 0, 0);
    }
  }

  if constexpr (MODE == 0) {
    #pragma unroll
    for (int mt = 0; mt < 4; ++mt) {
      int grow0 = m0 + wm + mt * 16 + quad * 4;
      #pragma unroll
      for (int nt = 0; nt < 2; ++nt) {
        int gcol = n0 + wn + nt * 16 + c;
        #pragma unroll
        for (int r = 0; r < 4; ++r)
          C[(size_t)(grow0 + r) * DMODEL + gcol] = acc[mt * 2 + nt][r];
      }
    }
  } else {
    const int whichblk = n0 >> 10;
    if (whichblk == 2) {
      #pragma unroll
      for (int mt = 0; mt < 4; ++mt) {
        int grow0 = m0 + wm + mt * 16 + quad * 4;
        int b = grow0 >> 11, s0 = grow0 & 2047;
        #pragma unroll
        for (int nt = 0; nt < 4; ++nt) {
          int cc = (n0 + wn + nt * 16 + c) & 1023;
          int hh = cc >> 6, dk = cc & 63;
          f32x4_t v4 = acc[mt * 4 + nt];
          ushort4 o;
          o.x = f2b(v4[0]); o.y = f2b(v4[1]); o.z = f2b(v4[2]); o.w = f2b(v4[3]);
          *(ushort4*)(vt16 + (((size_t)(b * NH + hh)) * DK + dk) * S_LEN + s0) = o;
        }
      }
    } else {
      u16* tb = (w & 1) ? Bs : As;
      const int base_mw = m0 + wm;
      const int bb = base_mw >> 11, s0g = base_mw & 2047;
      const int cc = (n0 + wn) & 1023;
      const int hh = cc >> 6;
      u16* qk = (whichblk == 0 ? q16 : k16) + (((size_t)(bb * NH + hh)) * S_LEN + s0g) * DK;
      __syncthreads();   // all frag reads of As/Bs complete
      #pragma unroll
      for (int round = 0; round < 2; ++round) {
        if ((w >> 1) == round) {
          #pragma unroll
          for (int mt = 0; mt < 4; ++mt)
            #pragma unroll
            for (int nt = 0; nt < 4; ++nt)
              #pragma unroll
              for (int r = 0; r < 4; ++r)
                tb[(mt * 16 + quad * 4 + r) * 72 + nt * 16 + c] = f2b(acc[mt * 4 + nt][r]);
          #pragma unroll
          for (int i = 0; i < 8; ++i) {
            int lrow = i * 8 + (l >> 3);
            int chk = l & 7;
            uint4 vv = *(const uint4*)(tb + lrow * 72 + chk * 8);
            *(uint4*)(qk + (size_t)lrow * DK + chk * 8) = vv;
          }
        }
        __syncthreads();
      }
    }
  }
}

// ---------------- MFMA flash attention (R5-proven, ~52 us): 128-q blocks, KVBLK=128, XCD swizzle ----------------
// 512 threads = 8 waves = 4 q-groups (32 q) x 2 key-halves (64 keys = 2 x 32-key chunks).
// Achieved occupancy is invariant at ~32% for 16- and 32-wave/CU caps (R5/R7 evidence) -> this
// configuration is the empirical optimum of the structure family; do not re-trade staging for TLP.
#define KSTR 72    // K row stride in u16 (144 B), R3-proven conflict-free
#define VSTR 136   // V^T row stride in u16 (272 B), same %32-word class as KSTR
__global__ __launch_bounds__(512, 4) void attn_mfma_kernel(const u16* __restrict__ q,
                                                           const u16* __restrict__ k,
                                                           const u16* __restrict__ vt,
                                                           const float* __restrict__ btab,
                                                           u16* __restrict__ ctx) {
  __shared__ __align__(16) char smem[37376];
  u16*   Ks   = (u16*)smem;                   // [128][KSTR]  18432 B
  u16*   Vts  = (u16*)(smem + 18432);         // [64][VSTR]   17408 B
  float* band = (float*)(smem + 35840);       // [256]         1024 B
  float* lpx  = (float*)(smem + 36864);       // [4][32]        512 B

  const int t = threadIdx.x;
  const int w = t >> 6, l = t & 63;
  const int c32 = l & 31, h32 = l >> 5;
  const int grp = w >> 1, kh = w & 1;

  // bijective XCD swizzle: orig%8 = XCD (round-robin dispatch) -> contiguous bh-major chunk
  const int orig = blockIdx.x;                 // 0..511
  const int swz = (orig & 7) * 64 + (orig >> 3);
  const int bh = swz >> 4;                     // 0..31
  const int q0 = (swz & 15) * 128;
  const int h = bh & (NH - 1), b = bh >> 4;

  const u16* qb = q + (size_t)bh * S_LEN * DK;
  const u16* kb = k + (size_t)bh * S_LEN * DK;
  const u16* vb = vt + (size_t)bh * DK * S_LEN;
  const float* btp = btab + h * 4095 + (2047 - 127 - q0);

  // Q fragments (B operand of 32x32x16): lane holds Q[q = c32][dk = kb4*16 + h32*8 + j]
  bf16x8_t qfrag[4];
  {
    const u16* qp = qb + (size_t)(q0 + grp * 32 + c32) * DK + h32 * 8;
    qfrag[0] = *(const bf16x8_t*)(qp);
    qfrag[1] = *(const bf16x8_t*)(qp + 16);
    qfrag[2] = *(const bf16x8_t*)(qp + 32);
    qfrag[3] = *(const bf16x8_t*)(qp + 48);
  }

  float lp = 0.f;
  f32x16_t O0 = {}, O1 = {};   // O: row=q=(r&3)+8*(r>>2)+4*h32, col=dk=dh*32+c32

  // staging (512 threads, 4 x uint4 each): K 128x64, V^T 64x128
  const int ksr = t >> 2;             // 0..127
  const int ksc = (t & 3) * 8;        // 0..24
  const u16* kgp = kb + (size_t)ksr * DK + ksc;
  u16* Kl = Ks + ksr * KSTR + ksc;
  const int vsr = t >> 3;             // 0..63
  const int vsc = (t & 7) * 8;        // 0..56
  const u16* vgp = vb + (size_t)vsr * S_LEN + vsc;
  u16* Vl = Vts + vsr * VSTR + vsc;

  uint4 kr0 = *(const uint4*)kgp;
  uint4 kr1 = *(const uint4*)(kgp + 32);
  uint4 vr0 = *(const uint4*)vgp;
  uint4 vr1 = *(const uint4*)(vgp + 64);
  float br = (t < 256) ? btp[t] : 0.f;

  const int krA = (kh * 64 + c32) * KSTR + h32 * 8;           // chunk A K-frag base
  const int bndcA = 127 + kh * 64 + 4 * h32 - grp * 32 - c32; // chunk A band base

  for (int kt = 0; kt < S_LEN; kt += 128) {
    *(uint4*)Kl = kr0;        *(uint4*)(Kl + 32) = kr1;
    *(uint4*)Vl = vr0;        *(uint4*)(Vl + 64) = vr1;
    if (t < 256) band[t] = br;
    __syncthreads();
    if (kt + 128 < S_LEN) {
      kr0 = *(const uint4*)(kgp + (size_t)(kt + 128) * DK);
      kr1 = *(const uint4*)(kgp + (size_t)(kt + 128) * DK + 32);
      vr0 = *(const uint4*)(vgp + (kt + 128));
      vr1 = *(const uint4*)(vgp + (kt + 128) + 64);
      br = (t < 256) ? btp[kt + 128 + t] : 0.f;
    }
    const int D = kt - q0;
    const bool far = (D >= 256) || (D <= -256);

    // QK^T (swapped), two independent 32-key chunks
    f32x16_t sA = {}, sB = {};
    __builtin_amdgcn_s_setprio(1);
    #pragma unroll
    for (int kb4 = 0; kb4 < 4; ++kb4) {
      bf16x8_t kfA = *(const bf16x8_t*)(Ks + krA + kb4 * 16);
      sA = __builtin_amdgcn_mfma_f32_32x32x16_bf16(kfA, qfrag[kb4], sA, 0, 0, 0);
    }
    #pragma unroll
    for (int kb4 = 0; kb4 < 4; ++kb4) {
      bf16x8_t kfB = *(const bf16x8_t*)(Ks + krA + 32 * KSTR + kb4 * 16);
      sB = __builtin_amdgcn_mfma_f32_32x32x16_bf16(kfB, qfrag[kb4], sB, 0, 0, 0);
    }
    __builtin_amdgcn_s_setprio(0);

    const float bfc = band[127];

    // ---- chunk A: softmax + pack + PV ----
    {
      float p[16];
      if (far) {
        #pragma unroll
        for (int r = 0; r < 16; ++r)
          p[r] = fexp2(fmaf(sA[r], LOG2E, bfc));
      } else {
        #pragma unroll
        for (int r = 0; r < 16; ++r)
          p[r] = fexp2(fmaf(sA[r], LOG2E, band[bndcA + (r & 3) + 8 * (r >> 2)]));
      }
      #pragma unroll
      for (int r = 0; r < 16; ++r)
        lp += p[r];
      union PW { u32 wds[4]; bf16x8_t v; } pa0, pa1;
      u32 x, y;
      x = cvtpk(p[0], p[1]);   y = cvtpk(p[4], p[5]);   plswap(x, y);
      pa0.wds[0] = x; pa0.wds[2] = y;
      x = cvtpk(p[2], p[3]);   y = cvtpk(p[6], p[7]);   plswap(x, y);
      pa0.wds[1] = x; pa0.wds[3] = y;
      x = cvtpk(p[8], p[9]);   y = cvtpk(p[12], p[13]); plswap(x, y);
      pa1.wds[0] = x; pa1.wds[2] = y;
      x = cvtpk(p[10], p[11]); y = cvtpk(p[14], p[15]); plswap(x, y);
      pa1.wds[1] = x; pa1.wds[3] = y;
      __builtin_amdgcn_s_setprio(1);
      bf16x8_t vf00 = *(const bf16x8_t*)(Vts + (c32)      * VSTR + kh * 64 + h32 * 8);
      bf16x8_t vf01 = *(const bf16x8_t*)(Vts + (32 + c32) * VSTR + kh * 64 + h32 * 8);
      O0 = __builtin_amdgcn_mfma_f32_32x32x16_bf16(pa0.v, vf00, O0, 0, 0, 0);
      O1 = __builtin_amdgcn_mfma_f32_32x32x16_bf16(pa0.v, vf01, O1, 0, 0, 0);
      bf16x8_t vf10 = *(const bf16x8_t*)(Vts + (c32)      * VSTR + kh * 64 + 16 + h32 * 8);
      bf16x8_t vf11 = *(const bf16x8_t*)(Vts + (32 + c32) * VSTR + kh * 64 + 16 + h32 * 8);
      O0 = __builtin_amdgcn_mfma_f32_32x32x16_bf16(pa1.v, vf10, O0, 0, 0, 0);
      O1 = __builtin_amdgcn_mfma_f32_32x32x16_bf16(pa1.v, vf11, O1, 0, 0, 0);
      __builtin_amdgcn_s_setprio(0);
    }

    // ---- chunk B (keys +32): softmax + pack + PV ----
    {
      float p[16];
      if (far) {
        #pragma unroll
        for (int r = 0; r < 16; ++r)
          p[r] = fexp2(fmaf(sB[r], LOG2E, bfc));
      } else {
        #pragma unroll
        for (int r = 0; r < 16; ++r)
          p[r] = fexp2(fmaf(sB[r], LOG2E, band[bndcA + 32 + (r & 3) + 8 * (r >> 2)]));
      }
      #pragma unroll
      for (int r = 0; r < 16; ++r)
        lp += p[r];
      union PW { u32 wds[4]; bf16x8_t v; } pa0, pa1;
      u32 x, y;
      x = cvtpk(p[0], p[1]);   y = cvtpk(p[4], p[5]);   plswap(x, y);
      pa0.wds[0] = x; pa0.wds[2] = y;
      x = cvtpk(p[2], p[3]);   y = cvtpk(p[6], p[7]);   plswap(x, y);
      pa0.wds[1] = x; pa0.wds[3] = y;
      x = cvtpk(p[8], p[9]);   y = cvtpk(p[12], p[13]); plswap(x, y);
      pa1.wds[0] = x; pa1.wds[2] = y;
      x = cvtpk(p[10], p[11]); y = cvtpk(p[14], p[15]); plswap(x, y);
      pa1.wds[1] = x; pa1.wds[3] = y;
      __builtin_amdgcn_s_setprio(1);
      bf16x8_t vf00 = *(const bf16x8_t*)(Vts + (c32)      * VSTR + kh * 64 + 32 + h32 * 8);
      bf16x8_t vf01 = *(const bf16x8_t*)(Vts + (32 + c32) * VSTR + kh * 64 + 32 + h32 * 8);
      O0 = __builtin_amdgcn_mfma_f32_32x32x16_bf16(pa0.v, vf00, O0, 0, 0, 0);
      O1 = __builtin_amdgcn_mfma_f32_32x32x16_bf16(pa0.v, vf01, O1, 0, 0, 0);
      bf16x8_t vf10 = *(const bf16x8_t*)(Vts + (c32)      * VSTR + kh * 64 + 48 + h32 * 8);
      bf16x8_t vf11 = *(const bf16x8_t*)(Vts + (32 + c32) * VSTR + kh * 64 + 48 + h32 * 8);
      O0 = __builtin_amdgcn_mfma_f32_32x32x16_bf16(pa1.v, vf10, O0, 0, 0, 0);
      O1 = __builtin_amdgcn_mfma_f32_32x32x16_bf16(pa1.v, vf11, O1, 0, 0, 0);
      __builtin_amdgcn_s_setprio(0);
    }
    __syncthreads();   // all reads of Ks/Vts/band done before next iter's writes
  }

  // ---- epilogue: combine key-half partials; Ored aliases dead Ks/Vts region (33792 <= 35840 B) ----
  lp += __shfl_xor(lp, 32, 64);
  float (*Ored)[64][33] = (float (*)[64][33])smem;

  if (kh == 1) {
    #pragma unroll
    for (int r = 0; r < 16; ++r) {
      Ored[grp][l][r]      = O0[r];
      Ored[grp][l][16 + r] = O1[r];
    }
    if (l < 32) lpx[grp * 32 + l] = lp;
  }
  __syncthreads();
  if (kh == 0) {
    lp += lpx[grp * 32 + c32];
    float rv = 1.0f / lp;            // valid in every lane for q = c32
    #pragma unroll
    for (int r = 0; r < 16; ++r) {
      int qr = (r & 3) + 8 * (r >> 2) + 4 * h32;     // q within group
      float inv = __shfl(rv, qr, 64);
      float o0 = O0[r] + Ored[grp][l][r];
      float o1 = O1[r] + Ored[grp][l][16 + r];
      int s = q0 + grp * 32 + qr;
      u16* cp = ctx + ((size_t)(b * S_LEN + s)) * DMODEL + h * DK;
      cp[c32]      = f2b(o0 * inv);
      cp[32 + c32] = f2b(o1 * inv);
    }
  }
}

extern "C" void kernel_launch(void* const* d_in, const int* in_sizes, int n_in,
                              void* d_out, int out_size, void* d_ws, size_t ws_size,
                              hipStream_t stream) {
  const float* x   = (const float*)d_in[0];
  const float* Wq  = (const float*)d_in[1];
  const float* Wk  = (const float*)d_in[2];
  const float* Wv  = (const float*)d_in[3];
  const float* Wo  = (const float*)d_in[4];
  const float* rel = (const float*)d_in[5];
  float* out = (float*)d_out;

  char* ws = (char*)d_ws;
  size_t off = 0;
  auto carve = [&](size_t bytes) -> char* {
    char* p = ws + off;
    off += (bytes + 255) & ~(size_t)255;
    return p;
  };
  u16*   xb   = (u16*)  carve((size_t)MROWS * DMODEL * 2);       // x bf16
  u16*   Wall = (u16*)  carve((size_t)3 * DMODEL * DMODEL * 2);  // [Wq^T;Wk^T;Wv^T] bf16 [3072][1024]
  u16*   Wto  = (u16*)  carve((size_t)DMODEL * DMODEL * 2);
  u16*   qb16 = (u16*)  carve((size_t)4194304 * 2);              // [bh][s][64] bf16
  u16*   kb16 = (u16*)  carve((size_t)4194304 * 2);
  u16*   vt16 = (u16*)  carve((size_t)4194304 * 2);              // [bh][64][s] bf16
  float* btab = (float*)carve(((size_t)NH * 4095 + 256) * 4);    // +tail slack (band stage)
  u16*   ctxb = (u16*)  carve((size_t)4194304 * 2);              // [b][s][1024] bf16

  prep_kernel<<<8448, 256, 0, stream>>>(x, Wq, Wk, Wv, Wo, rel, xb, Wall, Wto, btab);

  dim3 qkvgrid(32, 24);  // M/128, 3072/128
  gemm128_kernel<1><<<qkvgrid, 256, 0, stream>>>(xb, Wall, nullptr, qb16, kb16, vt16);

  attn_mfma_kernel<<<512, 512, 0, stream>>>(qb16, kb16, vt16, btab, ctxb);

  dim3 ogrid(32, 16);    // M/128, 1024/64
  gemm128_kernel<0><<<ogrid, 256, 0, stream>>>(ctxb, Wto, out, nullptr, nullptr, nullptr);
}

// Round 12
// 179.547 us; speedup vs baseline: 1.0867x; 1.0196x over previous
//
#include <hip/hip_runtime.h>
#include <math.h>

typedef unsigned short u16;
typedef unsigned int u32;
typedef __attribute__((ext_vector_type(8))) short bf16x8_t;
typedef __attribute__((ext_vector_type(4))) float f32x4_t;
typedef __attribute__((ext_vector_type(16))) float f32x16_t;

#define S_LEN  2048
#define NH     16
#define DK     64
#define DMODEL 1024
#define MROWS  4096   // B*S
#define LOG2E  1.44269504088896f

__device__ inline u16 f2b(float f) {
  union { float f; u32 u; } c; c.f = f;
  u32 u = c.u;
  return (u16)((u + 0x7fffu + ((u >> 16) & 1u)) >> 16);  // RNE bf16
}

__device__ __forceinline__ float fexp2(float x) {
#if __has_builtin(__builtin_amdgcn_exp2f)
  return __builtin_amdgcn_exp2f(x);
#else
  return exp2f(x);
#endif
}

__device__ __forceinline__ u32 cvtpk(float lo, float hi) {
  u32 r;
  asm("v_cvt_pk_bf16_f32 %0, %1, %2" : "=v"(r) : "v"(lo), "v"(hi));
  return r;
}

// swap x's high-32-lane half with y's low-32-lane half (gfx950 v_permlane32_swap_b32)
__device__ __forceinline__ void plswap(u32 &x, u32 &y) {
  asm("v_permlane32_swap_b32 %0, %1" : "+v"(x), "+v"(y));
}

// ---------------- global -> LDS DMA: wave-uniform LDS base, lane deposits 16B at base + lane*16 ----------------
__device__ __forceinline__ void stage16(const u16* gp_lane, u16* lds_base) {
#if __has_builtin(__builtin_amdgcn_global_load_lds)
  __builtin_amdgcn_global_load_lds((const __attribute__((address_space(1))) u32*)gp_lane,
                                   (__attribute__((address_space(3))) u32*)lds_base, 16, 0, 0);
#else
  *(uint4*)(lds_base + (threadIdx.x & 63) * 8) = *(const uint4*)gp_lane;
#endif
}

// ---------------- fused prep: cast x, transpose+cast 4 weights, bias table ----------------
__global__ void prep_kernel(const float* __restrict__ x,
                            const float* __restrict__ Wq, const float* __restrict__ Wk,
                            const float* __restrict__ Wv, const float* __restrict__ Wo,
                            const float* __restrict__ rel,
                            u16* __restrict__ xb, u16* __restrict__ Wall,
                            u16* __restrict__ Wto, float* __restrict__ btab) {
  __shared__ float tile[32][33];
  const int bid = blockIdx.x, t = threadIdx.x;
  if (bid < 4096) {
    int i = (bid * 256 + t) * 4;
    float4 v = *(const float4*)(x + i);
    ushort4 o;
    o.x = f2b(v.x); o.y = f2b(v.y); o.z = f2b(v.z); o.w = f2b(v.w);
    *(ushort4*)(xb + i) = o;
  } else if (bid < 8192) {
    int bid2 = bid - 4096;
    int z = bid2 >> 10, rem = bid2 & 1023;
    const float* W; u16* Wt;
    switch (z) {
      case 0: W = Wq; Wt = Wall; break;
      case 1: W = Wk; Wt = Wall + (size_t)DMODEL * DMODEL; break;
      case 2: W = Wv; Wt = Wall + (size_t)2 * DMODEL * DMODEL; break;
      default: W = Wo; Wt = Wto; break;
    }
    int bc = (rem & 31) * 32, br = (rem >> 5) * 32;
    int tx = t & 31, ty = t >> 5;
    #pragma unroll
    for (int yy = 0; yy < 32; yy += 8)
      tile[ty + yy][tx] = W[(size_t)(br + ty + yy) * DMODEL + bc + tx];
    __syncthreads();
    #pragma unroll
    for (int yy = 0; yy < 32; yy += 8)
      Wt[(size_t)(bc + ty + yy) * DMODEL + br + tx] = f2b(tile[tx][ty + yy]);
  } else {
    // bias table: btab[h][delta+2047] = (bias(h,delta) - 16) * log2(e)   [exp2-domain]
    int idx = (bid - 8192) * 256 + t;
    if (idx < NH * 4095) {
      int h = idx / 4095;
      int dpos = idx - h * 4095;
      int delta = dpos - 2047;               // j - i; reference n = i - j
      int ret = (delta > 0) ? 16 : 0;
      int n = delta < 0 ? -delta : delta;
      int bucket;
      if (n < 8) {
        bucket = ret + n;
      } else {
        float vf = logf((float)n * 0.125f) / 2.7725887222397811f * 8.0f;
        int vil = 8 + (int)vf;
        bucket = ret + (vil < 15 ? vil : 15);
      }
      btab[idx] = (rel[bucket * NH + h] - 16.0f) * LOG2E;
    }
  }
}

// ---------------- bf16 MFMA GEMM ----------------
// MODE 1: fused QKV, 128x128 tile, BK=32, [128][32] conflict-free layout, global_load_lds DMA,
//         2 barriers/K-step, grid (32,24)=768 blocks=3/CU. R8-proven optimum of this family:
//         BK=64 linear (R9, 9.5M conflicts), BK=64 swizzled (R10, -11 us), and 2-phase dbuf
//         (R11, null -- m99/m100 reproduced: wave-level overlap already hides the drain) all lose.
// MODE 0: out-projection, 128x64 tile, grid (32,16)=512 blocks=2/CU; manual staging + register
//         prefetch (R8-proven, -5 us vs 128x128 @ 1/CU).
#define GSTR 56   // manual-path LDS row stride (112 B): 16B-aligned, 2-way bank aliasing (free)
template <int MODE>
__global__ __launch_bounds__(256) void gemm128_kernel(const u16* __restrict__ A,
                                                      const u16* __restrict__ Bt,
                                                      float* __restrict__ C,
                                                      u16* __restrict__ q16,
                                                      u16* __restrict__ k16,
                                                      u16* __restrict__ vt16) {
  constexpr int ABSZ = (MODE == 1) ? 4608 : 128 * GSTR;
  constexpr int BSZ  = (MODE == 1) ? 4608 : 64 * GSTR;
  constexpr int FSTR = (MODE == 1) ? 32 : GSTR;
  __shared__ __align__(16) u16 As[ABSZ];
  __shared__ __align__(16) u16 Bs[BSZ];
  const int t = threadIdx.x, w = t >> 6, l = t & 63;
  const int c = l & 15, quad = l >> 4;
  const int m0 = blockIdx.x * 128;
  const int n0 = blockIdx.y * ((MODE == 1) ? 128 : 64);
  const int wm = (w & 1) * 64;
  const int wn = (w >> 1) * ((MODE == 1) ? 64 : 32);

  f32x4_t acc[16] = {};

  if constexpr (MODE == 1) {
    const int sr = l >> 2;
    const int k8 = (l & 3) * 8;
    const u16* Ag0 = A  + (size_t)(m0 + w * 32 + sr) * DMODEL + k8;
    const u16* Ag1 = Ag0 + (size_t)16 * DMODEL;
    const u16* Bg0 = Bt + (size_t)(n0 + w * 32 + sr) * DMODEL + k8;
    const u16* Bg1 = Bg0 + (size_t)16 * DMODEL;
    u16* Al = As + w * 1024;
    u16* Bl = Bs + w * 1024;
    for (int k0 = 0; k0 < DMODEL; k0 += 32) {
      __syncthreads();
      stage16(Ag0 + k0, Al);
      stage16(Ag1 + k0, Al + 512);
      stage16(Bg0 + k0, Bl);
      stage16(Bg1 + k0, Bl + 512);
      __syncthreads();
      bf16x8_t af[4], bfr[4];
      #pragma unroll
      for (int i = 0; i < 4; ++i) {
        af[i]  = *(const bf16x8_t*)(As + (wm + i * 16 + c) * FSTR + quad * 8);
        bfr[i] = *(const bf16x8_t*)(Bs + (wn + i * 16 + c) * FSTR + quad * 8);
      }
      #pragma unroll
      for (int mt = 0; mt < 4; ++mt)
        #pragma unroll
        for (int nt = 0; nt < 4; ++nt)
          acc[mt * 4 + nt] = __builtin_amdgcn_mfma_f32_16x16x32_bf16(af[mt], bfr[nt], acc[mt * 4 + nt], 0, 0, 0);
    }
  } else {
    // manual staging + register prefetch; A: 128x32, B: 64x32 per K-step
    const int sr = t >> 2;              // 0..63
    const int k8 = (t & 3) * 8;
    const u16* Ag0 = A  + (size_t)(m0 + sr) * DMODEL + k8;
    const u16* Ag1 = Ag0 + (size_t)64 * DMODEL;
    const u16* Bg0 = Bt + (size_t)(n0 + sr) * DMODEL + k8;
    u16* Al0 = As + sr * GSTR + k8;
    u16* Al1 = Al0 + 64 * GSTR;
    u16* Bl0 = Bs + sr * GSTR + k8;

    uint4 a0 = *(const uint4*)Ag0, a1 = *(const uint4*)Ag1;
    uint4 b0 = *(const uint4*)Bg0;
    for (int k0 = 0; k0 < DMODEL; k0 += 32) {
      __syncthreads();
      *(uint4*)Al0 = a0; *(uint4*)Al1 = a1;
      *(uint4*)Bl0 = b0;
      __syncthreads();
      if (k0 + 32 < DMODEL) {
        a0 = *(const uint4*)(Ag0 + k0 + 32);
        a1 = *(const uint4*)(Ag1 + k0 + 32);
        b0 = *(const uint4*)(Bg0 + k0 + 32);
      }
      bf16x8_t af[4], bfr[2];
      #pragma unroll
      for (int i = 0; i < 4; ++i)
        af[i] = *(const bf16x8_t*)(As + (wm + i * 16 + c) * FSTR + quad * 8);
      #pragma unroll
      for (int i = 0; i < 2; ++i)
        bfr[i] = *(const bf16x8_t*)(Bs + (wn + i * 16 + c) * FSTR + quad * 8);
      #pragma unroll
      for (int mt = 0; mt < 4; ++mt)
        #pragma unroll
        for (int nt = 0; nt < 2; ++nt)
          acc[mt * 2 + nt] = __builtin_amdgcn_mfma_f32_16x16x32_bf16(af[mt], bfr[nt], acc[mt * 2 + nt], 0, 0, 0);
    }
  }

  if constexpr (MODE == 0) {
    #pragma unroll
    for (int mt = 0; mt < 4; ++mt) {
      int grow0 = m0 + wm + mt * 16 + quad * 4;
      #pragma unroll
      for (int nt = 0; nt < 2; ++nt) {
        int gcol = n0 + wn + nt * 16 + c;
        #pragma unroll
        for (int r = 0; r < 4; ++r)
          C[(size_t)(grow0 + r) * DMODEL + gcol] = acc[mt * 2 + nt][r];
      }
    }
  } else {
    const int whichblk = n0 >> 10;
    if (whichblk == 2) {
      #pragma unroll
      for (int mt = 0; mt < 4; ++mt) {
        int grow0 = m0 + wm + mt * 16 + quad * 4;
        int b = grow0 >> 11, s0 = grow0 & 2047;
        #pragma unroll
        for (int nt = 0; nt < 4; ++nt) {
          int cc = (n0 + wn + nt * 16 + c) & 1023;
          int hh = cc >> 6, dk = cc & 63;
          f32x4_t v4 = acc[mt * 4 + nt];
          ushort4 o;
          o.x = f2b(v4[0]); o.y = f2b(v4[1]); o.z = f2b(v4[2]); o.w = f2b(v4[3]);
          *(ushort4*)(vt16 + (((size_t)(b * NH + hh)) * DK + dk) * S_LEN + s0) = o;
        }
      }
    } else {
      u16* tb = (w & 1) ? Bs : As;
      const int base_mw = m0 + wm;
      const int bb = base_mw >> 11, s0g = base_mw & 2047;
      const int cc = (n0 + wn) & 1023;
      const int hh = cc >> 6;
      u16* qk = (whichblk == 0 ? q16 : k16) + (((size_t)(bb * NH + hh)) * S_LEN + s0g) * DK;
      __syncthreads();   // all frag reads of As/Bs complete
      #pragma unroll
      for (int round = 0; round < 2; ++round) {
        if ((w >> 1) == round) {
          #pragma unroll
          for (int mt = 0; mt < 4; ++mt)
            #pragma unroll
            for (int nt = 0; nt < 4; ++nt)
              #pragma unroll
              for (int r = 0; r < 4; ++r)
                tb[(mt * 16 + quad * 4 + r) * 72 + nt * 16 + c] = f2b(acc[mt * 4 + nt][r]);
          #pragma unroll
          for (int i = 0; i < 8; ++i) {
            int lrow = i * 8 + (l >> 3);
            int chk = l & 7;
            uint4 vv = *(const uint4*)(tb + lrow * 72 + chk * 8);
            *(uint4*)(qk + (size_t)lrow * DK + chk * 8) = vv;
          }
        }
        __syncthreads();
      }
    }
  }
}

// ---------------- MFMA flash attention (R5-proven, ~52 us): 128-q blocks, KVBLK=128, XCD swizzle ----------------
// 512 threads = 8 waves = 4 q-groups (32 q) x 2 key-halves (64 keys = 2 x 32-key chunks).
// Achieved occupancy is invariant at ~32% for 16- and 32-wave/CU caps (R5/R7 evidence) -> this
// configuration is the empirical optimum of the structure family; do not re-trade staging for TLP.
#define KSTR 72    // K row stride in u16 (144 B), R3-proven conflict-free
#define VSTR 136   // V^T row stride in u16 (272 B), same %32-word class as KSTR
__global__ __launch_bounds__(512, 4) void attn_mfma_kernel(const u16* __restrict__ q,
                                                           const u16* __restrict__ k,
                                                           const u16* __restrict__ vt,
                                                           const float* __restrict__ btab,
                                                           u16* __restrict__ ctx) {
  __shared__ __align__(16) char smem[37376];
  u16*   Ks   = (u16*)smem;                   // [128][KSTR]  18432 B
  u16*   Vts  = (u16*)(smem + 18432);         // [64][VSTR]   17408 B
  float* band = (float*)(smem + 35840);       // [256]         1024 B
  float* lpx  = (float*)(smem + 36864);       // [4][32]        512 B

  const int t = threadIdx.x;
  const int w = t >> 6, l = t & 63;
  const int c32 = l & 31, h32 = l >> 5;
  const int grp = w >> 1, kh = w & 1;

  // bijective XCD swizzle: orig%8 = XCD (round-robin dispatch) -> contiguous bh-major chunk
  const int orig = blockIdx.x;                 // 0..511
  const int swz = (orig & 7) * 64 + (orig >> 3);
  const int bh = swz >> 4;                     // 0..31
  const int q0 = (swz & 15) * 128;
  const int h = bh & (NH - 1), b = bh >> 4;

  const u16* qb = q + (size_t)bh * S_LEN * DK;
  const u16* kb = k + (size_t)bh * S_LEN * DK;
  const u16* vb = vt + (size_t)bh * DK * S_LEN;
  const float* btp = btab + h * 4095 + (2047 - 127 - q0);

  // Q fragments (B operand of 32x32x16): lane holds Q[q = c32][dk = kb4*16 + h32*8 + j]
  bf16x8_t qfrag[4];
  {
    const u16* qp = qb + (size_t)(q0 + grp * 32 + c32) * DK + h32 * 8;
    qfrag[0] = *(const bf16x8_t*)(qp);
    qfrag[1] = *(const bf16x8_t*)(qp + 16);
    qfrag[2] = *(const bf16x8_t*)(qp + 32);
    qfrag[3] = *(const bf16x8_t*)(qp + 48);
  }

  float lp = 0.f;
  f32x16_t O0 = {}, O1 = {};   // O: row=q=(r&3)+8*(r>>2)+4*h32, col=dk=dh*32+c32

  // staging (512 threads, 4 x uint4 each): K 128x64, V^T 64x128
  const int ksr = t >> 2;             // 0..127
  const int ksc = (t & 3) * 8;        // 0..24
  const u16* kgp = kb + (size_t)ksr * DK + ksc;
  u16* Kl = Ks + ksr * KSTR + ksc;
  const int vsr = t >> 3;             // 0..63
  const int vsc = (t & 7) * 8;        // 0..56
  const u16* vgp = vb + (size_t)vsr * S_LEN + vsc;
  u16* Vl = Vts + vsr * VSTR + vsc;

  uint4 kr0 = *(const uint4*)kgp;
  uint4 kr1 = *(const uint4*)(kgp + 32);
  uint4 vr0 = *(const uint4*)vgp;
  uint4 vr1 = *(const uint4*)(vgp + 64);
  float br = (t < 256) ? btp[t] : 0.f;

  const int krA = (kh * 64 + c32) * KSTR + h32 * 8;           // chunk A K-frag base
  const int bndcA = 127 + kh * 64 + 4 * h32 - grp * 32 - c32; // chunk A band base

  for (int kt = 0; kt < S_LEN; kt += 128) {
    *(uint4*)Kl = kr0;        *(uint4*)(Kl + 32) = kr1;
    *(uint4*)Vl = vr0;        *(uint4*)(Vl + 64) = vr1;
    if (t < 256) band[t] = br;
    __syncthreads();
    if (kt + 128 < S_LEN) {
      kr0 = *(const uint4*)(kgp + (size_t)(kt + 128) * DK);
      kr1 = *(const uint4*)(kgp + (size_t)(kt + 128) * DK + 32);
      vr0 = *(const uint4*)(vgp + (kt + 128));
      vr1 = *(const uint4*)(vgp + (kt + 128) + 64);
      br = (t < 256) ? btp[kt + 128 + t] : 0.f;
    }
    const int D = kt - q0;
    const bool far = (D >= 256) || (D <= -256);

    // QK^T (swapped), two independent 32-key chunks
    f32x16_t sA = {}, sB = {};
    __builtin_amdgcn_s_setprio(1);
    #pragma unroll
    for (int kb4 = 0; kb4 < 4; ++kb4) {
      bf16x8_t kfA = *(const bf16x8_t*)(Ks + krA + kb4 * 16);
      sA = __builtin_amdgcn_mfma_f32_32x32x16_bf16(kfA, qfrag[kb4], sA, 0, 0, 0);
    }
    #pragma unroll
    for (int kb4 = 0; kb4 < 4; ++kb4) {
      bf16x8_t kfB = *(const bf16x8_t*)(Ks + krA + 32 * KSTR + kb4 * 16);
      sB = __builtin_amdgcn_mfma_f32_32x32x16_bf16(kfB, qfrag[kb4], sB, 0, 0, 0);
    }
    __builtin_amdgcn_s_setprio(0);

    const float bfc = band[127];

    // ---- chunk A: softmax + pack + PV ----
    {
      float p[16];
      if (far) {
        #pragma unroll
        for (int r = 0; r < 16; ++r)
          p[r] = fexp2(fmaf(sA[r], LOG2E, bfc));
      } else {
        #pragma unroll
        for (int r = 0; r < 16; ++r)
          p[r] = fexp2(fmaf(sA[r], LOG2E, band[bndcA + (r & 3) + 8 * (r >> 2)]));
      }
      #pragma unroll
      for (int r = 0; r < 16; ++r)
        lp += p[r];
      union PW { u32 wds[4]; bf16x8_t v; } pa0, pa1;
      u32 x, y;
      x = cvtpk(p[0], p[1]);   y = cvtpk(p[4], p[5]);   plswap(x, y);
      pa0.wds[0] = x; pa0.wds[2] = y;
      x = cvtpk(p[2], p[3]);   y = cvtpk(p[6], p[7]);   plswap(x, y);
      pa0.wds[1] = x; pa0.wds[3] = y;
      x = cvtpk(p[8], p[9]);   y = cvtpk(p[12], p[13]); plswap(x, y);
      pa1.wds[0] = x; pa1.wds[2] = y;
      x = cvtpk(p[10], p[11]); y = cvtpk(p[14], p[15]); plswap(x, y);
      pa1.wds[1] = x; pa1.wds[3] = y;
      __builtin_amdgcn_s_setprio(1);
      bf16x8_t vf00 = *(const bf16x8_t*)(Vts + (c32)      * VSTR + kh * 64 + h32 * 8);
      bf16x8_t vf01 = *(const bf16x8_t*)(Vts + (32 + c32) * VSTR + kh * 64 + h32 * 8);
      O0 = __builtin_amdgcn_mfma_f32_32x32x16_bf16(pa0.v, vf00, O0, 0, 0, 0);
      O1 = __builtin_amdgcn_mfma_f32_32x32x16_bf16(pa0.v, vf01, O1, 0, 0, 0);
      bf16x8_t vf10 = *(const bf16x8_t*)(Vts + (c32)      * VSTR + kh * 64 + 16 + h32 * 8);
      bf16x8_t vf11 = *(const bf16x8_t*)(Vts + (32 + c32) * VSTR + kh * 64 + 16 + h32 * 8);
      O0 = __builtin_amdgcn_mfma_f32_32x32x16_bf16(pa1.v, vf10, O0, 0, 0, 0);
      O1 = __builtin_amdgcn_mfma_f32_32x32x16_bf16(pa1.v, vf11, O1, 0, 0, 0);
      __builtin_amdgcn_s_setprio(0);
    }

    // ---- chunk B (keys +32): softmax + pack + PV ----
    {
      float p[16];
      if (far) {
        #pragma unroll
        for (int r = 0; r < 16; ++r)
          p[r] = fexp2(fmaf(sB[r], LOG2E, bfc));
      } else {
        #pragma unroll
        for (int r = 0; r < 16; ++r)
          p[r] = fexp2(fmaf(sB[r], LOG2E, band[bndcA + 32 + (r & 3) + 8 * (r >> 2)]));
      }
      #pragma unroll
      for (int r = 0; r < 16; ++r)
        lp += p[r];
      union PW { u32 wds[4]; bf16x8_t v; } pa0, pa1;
      u32 x, y;
      x = cvtpk(p[0], p[1]);   y = cvtpk(p[4], p[5]);   plswap(x, y);
      pa0.wds[0] = x; pa0.wds[2] = y;
      x = cvtpk(p[2], p[3]);   y = cvtpk(p[6], p[7]);   plswap(x, y);
      pa0.wds[1] = x; pa0.wds[3] = y;
      x = cvtpk(p[8], p[9]);   y = cvtpk(p[12], p[13]); plswap(x, y);
      pa1.wds[0] = x; pa1.wds[2] = y;
      x = cvtpk(p[10], p[11]); y = cvtpk(p[14], p[15]); plswap(x, y);
      pa1.wds[1] = x; pa1.wds[3] = y;
      __builtin_amdgcn_s_setprio(1);
      bf16x8_t vf00 = *(const bf16x8_t*)(Vts + (c32)      * VSTR + kh * 64 + 32 + h32 * 8);
      bf16x8_t vf01 = *(const bf16x8_t*)(Vts + (32 + c32) * VSTR + kh * 64 + 32 + h32 * 8);
      O0 = __builtin_amdgcn_mfma_f32_32x32x16_bf16(pa0.v, vf00, O0, 0, 0, 0);
      O1 = __builtin_amdgcn_mfma_f32_32x32x16_bf16(pa0.v, vf01, O1, 0, 0, 0);
      bf16x8_t vf10 = *(const bf16x8_t*)(Vts + (c32)      * VSTR + kh * 64 + 48 + h32 * 8);
      bf16x8_t vf11 = *(const bf16x8_t*)(Vts + (32 + c32) * VSTR + kh * 64 + 48 + h32 * 8);
      O0 = __builtin_amdgcn_mfma_f32_32x32x16_bf16(pa1.v, vf10, O0, 0, 0, 0);
      O1 = __builtin_amdgcn_mfma_f32_32x32x16_bf16(pa1.v, vf11, O1, 0, 0, 0);
      __builtin_amdgcn_s_setprio(0);
    }
    __syncthreads();   // all reads of Ks/Vts/band done before next iter's writes
  }

  // ---- epilogue: combine key-half partials; Ored aliases dead Ks/Vts region (33792 <= 35840 B) ----
  lp += __shfl_xor(lp, 32, 64);
  float (*Ored)[64][33] = (float (*)[64][33])smem;

  if (kh == 1) {
    #pragma unroll
    for (int r = 0; r < 16; ++r) {
      Ored[grp][l][r]      = O0[r];
      Ored[grp][l][16 + r] = O1[r];
    }
    if (l < 32) lpx[grp * 32 + l] = lp;
  }
  __syncthreads();
  if (kh == 0) {
    lp += lpx[grp * 32 + c32];
    float rv = 1.0f / lp;            // valid in every lane for q = c32
    #pragma unroll
    for (int r = 0; r < 16; ++r) {
      int qr = (r & 3) + 8 * (r >> 2) + 4 * h32;     // q within group
      float inv = __shfl(rv, qr, 64);
      float o0 = O0[r] + Ored[grp][l][r];
      float o1 = O1[r] + Ored[grp][l][16 + r];
      int s = q0 + grp * 32 + qr;
      u16* cp = ctx + ((size_t)(b * S_LEN + s)) * DMODEL + h * DK;
      cp[c32]      = f2b(o0 * inv);
      cp[32 + c32] = f2b(o1 * inv);
    }
  }
}

extern "C" void kernel_launch(void* const* d_in, const int* in_sizes, int n_in,
                              void* d_out, int out_size, void* d_ws, size_t ws_size,
                              hipStream_t stream) {
  const float* x   = (const float*)d_in[0];
  const float* Wq  = (const float*)d_in[1];
  const float* Wk  = (const float*)d_in[2];
  const float* Wv  = (const float*)d_in[3];
  const float* Wo  = (const float*)d_in[4];
  const float* rel = (const float*)d_in[5];
  float* out = (float*)d_out;

  char* ws = (char*)d_ws;
  size_t off = 0;
  auto carve = [&](size_t bytes) -> char* {
    char* p = ws + off;
    off += (bytes + 255) & ~(size_t)255;
    return p;
  };
  u16*   xb   = (u16*)  carve((size_t)MROWS * DMODEL * 2);       // x bf16
  u16*   Wall = (u16*)  carve((size_t)3 * DMODEL * DMODEL * 2);  // [Wq^T;Wk^T;Wv^T] bf16 [3072][1024]
  u16*   Wto  = (u16*)  carve((size_t)DMODEL * DMODEL * 2);
  u16*   qb16 = (u16*)  carve((size_t)4194304 * 2);              // [bh][s][64] bf16
  u16*   kb16 = (u16*)  carve((size_t)4194304 * 2);
  u16*   vt16 = (u16*)  carve((size_t)4194304 * 2);              // [bh][64][s] bf16
  float* btab = (float*)carve(((size_t)NH * 4095 + 256) * 4);    // +tail slack (band stage)
  u16*   ctxb = (u16*)  carve((size_t)4194304 * 2);              // [b][s][1024] bf16

  prep_kernel<<<8448, 256, 0, stream>>>(x, Wq, Wk, Wv, Wo, rel, xb, Wall, Wto, btab);

  dim3 qkvgrid(32, 24);  // M/128, 3072/128
  gemm128_kernel<1><<<qkvgrid, 256, 0, stream>>>(xb, Wall, nullptr, qb16, kb16, vt16);

  attn_mfma_kernel<<<512, 512, 0, stream>>>(qb16, kb16, vt16, btab, ctxb);

  dim3 ogrid(32, 16);    // M/128, 1024/64
  gemm128_kernel<0><<<ogrid, 256, 0, stream>>>(ctxb, Wto, out, nullptr, nullptr, nullptr);
}